// Round 1
// baseline (2903.615 us; speedup 1.0000x reference)
//
#include <hip/hip_runtime.h>
#include <cstdint>

#define S_LEN 4096
#define D_DIM 256

// workspace layout (float offsets)
#define OFF_MINP 0
#define OFF_WPT  16
#define OFF_WEFF (OFF_WPT + 768*256)
#define OFF_C    (OFF_WEFF + 3*256*768)
#define OFF_HH   (OFF_C + 8*768*4096)
#define OFF_V    (OFF_HH + 8*2*256*4096)
#define OFF_U    (OFF_V + 8*256*4096)

__device__ __forceinline__ float wave_reduce_sum(float v) {
#pragma unroll
    for (int off = 32; off > 0; off >>= 1) v += __shfl_down(v, off, 64);
    return v;
}

// ---------------- min valid position per batch ----------------
__global__ __launch_bounds__(256) void k_minpos(const int* __restrict__ pos, float* __restrict__ minp)
{
    const int b = blockIdx.x;
    const int tid = threadIdx.x;
    int mn = 0x7fffffff;
    const int* p = pos + (size_t)b * S_LEN;
    for (int s = tid; s < S_LEN; s += 256) {
        const int v = p[s];
        if (v != -1) mn = min(mn, v);
    }
    __shared__ int red[256];
    red[tid] = mn;
    __syncthreads();
    for (int st = 128; st > 0; st >>= 1) {
        if (tid < st) red[tid] = min(red[tid], red[tid + st]);
        __syncthreads();
    }
    if (tid == 0) minp[b] = (float)red[0];
}

// ---------------- transpose W_proj (256x768) -> WpT (768x256) ----------------
__global__ __launch_bounds__(256) void k_wpt(const float* __restrict__ Wp, float* __restrict__ WpT)
{
    __shared__ float t[32][33];
    const int e0 = blockIdx.x * 32;   // 0..767
    const int d0 = blockIdx.y * 32;   // 0..255
    const int lx = threadIdx.x & 31, ly = threadIdx.x >> 5; // 32x8
#pragma unroll
    for (int q = 0; q < 4; ++q)
        t[ly + 8*q][lx] = Wp[(size_t)(d0 + ly + 8*q) * 768 + e0 + lx];
    __syncthreads();
#pragma unroll
    for (int q = 0; q < 4; ++q)
        WpT[(size_t)(e0 + ly + 8*q) * 256 + d0 + lx] = t[lx][ly + 8*q];
}

// ---------------- Weff[k][d][o] = sum_i WpT[g*256+i][d] * conv_w[o][i][k] ----------------
__global__ __launch_bounds__(256) void k_weff(const float* __restrict__ WpT, const float* __restrict__ cw,
                                              float* __restrict__ weff)
{
    const int o = blockIdx.x;       // 768
    const int d = threadIdx.x;      // 256
    const int g = o >> 8;
    __shared__ float cwrow[768];
    for (int i = threadIdx.x; i < 768; i += 256) cwrow[i] = cw[(size_t)o * 768 + i];
    __syncthreads();
    float a0 = 0.f, a1 = 0.f, a2 = 0.f;
    const float* wb = WpT + (size_t)(g * 256) * 256 + d;
#pragma unroll 4
    for (int i = 0; i < 256; ++i) {
        const float wv = wb[(size_t)i * 256];
        a0 += wv * cwrow[i*3+0];
        a1 += wv * cwrow[i*3+1];
        a2 += wv * cwrow[i*3+2];
    }
    weff[(size_t)(0*256 + d) * 768 + o] = a0;
    weff[(size_t)(1*256 + d) * 768 + o] = a1;
    weff[(size_t)(2*256 + d) * 768 + o] = a2;
}

// ---------------- c[b][o][s] = mask * (conv_b[o] + sum_{k,d} emb[b][s+k-1][d]*Weff[k][d][o]) ----------------
// 128(s) x 128(o) tile per block, fp32 outer-product 8x8 per thread.
__global__ __launch_bounds__(256, 2) void k_convgemm(
    const float* __restrict__ emb, const int* __restrict__ pos,
    const float* __restrict__ weff, const float* __restrict__ convb,
    float* __restrict__ c)
{
    const int b  = blockIdx.z;
    const int o0 = blockIdx.y * 128;
    const int s0 = blockIdx.x * 128;
    const int tid = threadIdx.x;
    __shared__ float Asm[64 * 132];   // [j(d-local)][s] stride 132
    __shared__ float Wsm[64 * 128];   // [j][o]
    const int s_sub = (tid & 15) * 8;
    const int o_sub = (tid >> 4) * 8;
    float acc[8][8];
#pragma unroll
    for (int i = 0; i < 8; ++i)
#pragma unroll
        for (int j = 0; j < 8; ++j) acc[i][j] = 0.f;

    for (int ch = 0; ch < 12; ++ch) {
        const int k  = ch >> 2;
        const int d0 = (ch & 3) * 64;
        // A tile: 128 s-rows x 64 d-cols, stored transposed [d][s]
        {
            const int sl = tid >> 1;          // 0..127
            const int dg = (tid & 1) * 32;    // 0 or 32
            const int rr = s0 + sl + k - 1;
            float4 v[8];
            if (rr >= 0 && rr < S_LEN) {
                const float4* src = (const float4*)(emb + ((size_t)b * S_LEN + rr) * D_DIM + d0 + dg);
#pragma unroll
                for (int q = 0; q < 8; ++q) v[q] = src[q];
            } else {
#pragma unroll
                for (int q = 0; q < 8; ++q) v[q] = make_float4(0.f,0.f,0.f,0.f);
            }
#pragma unroll
            for (int q = 0; q < 8; ++q) {
                Asm[(dg + q*4 + 0) * 132 + sl] = v[q].x;
                Asm[(dg + q*4 + 1) * 132 + sl] = v[q].y;
                Asm[(dg + q*4 + 2) * 132 + sl] = v[q].z;
                Asm[(dg + q*4 + 3) * 132 + sl] = v[q].w;
            }
        }
        // W tile: 64 j-rows x 128 o-cols
        {
            const int j  = tid >> 2;          // 0..63
            const int og = (tid & 3) * 32;    // 0,32,64,96
            const float4* src = (const float4*)(weff + ((size_t)(k * 256 + d0 + j)) * 768 + o0 + og);
            float4* dst = (float4*)&Wsm[j * 128 + og];
#pragma unroll
            for (int q = 0; q < 8; ++q) dst[q] = src[q];
        }
        __syncthreads();
#pragma unroll 4
        for (int j = 0; j < 64; ++j) {
            const float4 a0 = *(const float4*)&Asm[j * 132 + s_sub];
            const float4 a1 = *(const float4*)&Asm[j * 132 + s_sub + 4];
            const float4 w0 = *(const float4*)&Wsm[j * 128 + o_sub];
            const float4 w1 = *(const float4*)&Wsm[j * 128 + o_sub + 4];
            const float av[8] = {a0.x,a0.y,a0.z,a0.w,a1.x,a1.y,a1.z,a1.w};
            const float wv[8] = {w0.x,w0.y,w0.z,w0.w,w1.x,w1.y,w1.z,w1.w};
#pragma unroll
            for (int r = 0; r < 8; ++r)
#pragma unroll
                for (int cc = 0; cc < 8; ++cc) acc[r][cc] += av[r] * wv[cc];
        }
        __syncthreads();
    }
    // epilogue: +bias, *mask, store
    float msk[8];
#pragma unroll
    for (int r = 0; r < 8; ++r)
        msk[r] = (pos[(size_t)b * S_LEN + s0 + s_sub + r] != -1) ? 1.f : 0.f;
#pragma unroll
    for (int cc = 0; cc < 8; ++cc) {
        const int o = o0 + o_sub + cc;
        const float cb = convb[o];
        float* dst = c + ((size_t)(b * 768 + o)) * S_LEN + s0 + s_sub;
        float4 r0, r1;
        r0.x = (acc[0][cc] + cb) * msk[0]; r0.y = (acc[1][cc] + cb) * msk[1];
        r0.z = (acc[2][cc] + cb) * msk[2]; r0.w = (acc[3][cc] + cb) * msk[3];
        r1.x = (acc[4][cc] + cb) * msk[4]; r1.y = (acc[5][cc] + cb) * msk[5];
        r1.z = (acc[6][cc] + cb) * msk[6]; r1.w = (acc[7][cc] + cb) * msk[7];
        *(float4*)dst       = r0;
        *(float4*)(dst + 4) = r1;
    }
}

// ---------------- RoPE + FF + L1-normalize -> hh[b][i][d][s] ----------------
__global__ __launch_bounds__(256) void k_ff(
    const float* __restrict__ emb, const int* __restrict__ pos, const float* __restrict__ minp,
    const float* __restrict__ W1, const float* __restrict__ b1,
    const float* __restrict__ lng, const float* __restrict__ lnb,
    const float* __restrict__ W2, const float* __restrict__ b2,
    const float* __restrict__ ffs, float* __restrict__ hh)
{
    const int b   = blockIdx.y;
    const int s0  = blockIdx.x * 16;
    const int tid = threadIdx.x;
    __shared__ float tls[16 * 256];
    __shared__ float hls[16 * 256];
    __shared__ float mu_s[16], rs_s[16], sm0[16], sm1[16];

    // RoPE: each thread handles row r = tid>>4, 8 pairs starting at (tid&15)*8
    {
        const int r  = tid >> 4;
        const int j0 = (tid & 15) * 8;
        const int s  = s0 + r;
        const int p  = pos[(size_t)b * S_LEN + s];
        const float adj = (p == -1) ? -1.f : ((float)p - minp[b]);
        const float4* src = (const float4*)(emb + ((size_t)b * S_LEN + s) * D_DIM + j0 * 2);
        const float4 q0 = src[0], q1 = src[1], q2 = src[2], q3 = src[3];
        const float ev[16] = {q0.x,q0.y,q0.z,q0.w,q1.x,q1.y,q1.z,q1.w,
                              q2.x,q2.y,q2.z,q2.w,q3.x,q3.y,q3.z,q3.w};
        float* dst = &tls[r * 256 + j0 * 2];
#pragma unroll
        for (int jj = 0; jj < 8; ++jj) {
            const int j = j0 + jj;
            const float theta = expf(-(float)j * 0.07195578415606394f); // ln(10000)/128
            float sn, cs;
            sincosf(adj * theta, &sn, &cs);
            const float x1 = ev[2*jj], x2 = ev[2*jj+1];
            dst[2*jj]   = x1 * cs - x2 * sn;
            dst[2*jj+1] = x1 * sn + x2 * cs;
        }
    }
    __syncthreads();
    // h1 = t @ W1 + b1 ; col = tid, 16 rows
    float h1a[16];
#pragma unroll
    for (int r = 0; r < 16; ++r) h1a[r] = 0.f;
    for (int dd = 0; dd < 256; dd += 4) {
        const float w0 = W1[(size_t)(dd+0)*256 + tid];
        const float w1 = W1[(size_t)(dd+1)*256 + tid];
        const float w2 = W1[(size_t)(dd+2)*256 + tid];
        const float w3 = W1[(size_t)(dd+3)*256 + tid];
#pragma unroll
        for (int r = 0; r < 16; ++r) {
            const float4 t4 = *(const float4*)&tls[r*256 + dd];
            h1a[r] += t4.x*w0 + t4.y*w1 + t4.z*w2 + t4.w*w3;
        }
    }
    {
        const float bb = b1[tid];
#pragma unroll
        for (int r = 0; r < 16; ++r) hls[r*256 + tid] = h1a[r] + bb;
    }
    __syncthreads();
    // LayerNorm stats (4 rows per wave)
    {
        const int w = tid >> 6, lane = tid & 63;
#pragma unroll
        for (int rr = 0; rr < 4; ++rr) {
            const int r = w * 4 + rr;
            float s = 0.f, q = 0.f;
#pragma unroll
            for (int c4 = 0; c4 < 4; ++c4) {
                const float v = hls[r*256 + lane + c4*64];
                s += v; q += v*v;
            }
            s = wave_reduce_sum(s);
            q = wave_reduce_sum(q);
            if (lane == 0) {
                const float mu = s * (1.f/256.f);
                const float var = q * (1.f/256.f) - mu*mu;
                mu_s[r] = mu;
                rs_s[r] = rsqrtf(var + 1e-5f);
            }
        }
    }
    __syncthreads();
    // LN apply + exact gelu -> tls
    {
        const float g = lng[tid], be = lnb[tid];
#pragma unroll
        for (int r = 0; r < 16; ++r) {
            const float h = (hls[r*256 + tid] - mu_s[r]) * rs_s[r] * g + be;
            tls[r*256 + tid] = 0.5f * h * (1.f + erff(h * 0.7071067811865475f));
        }
    }
    __syncthreads();
    // h2 = gelu(h) @ W2 + b2, cols tid and tid+256
    float a0[16], a1[16];
#pragma unroll
    for (int r = 0; r < 16; ++r) { a0[r] = 0.f; a1[r] = 0.f; }
    for (int ee = 0; ee < 256; ee += 4) {
        float wA[4], wB[4];
#pragma unroll
        for (int q = 0; q < 4; ++q) {
            wA[q] = W2[(size_t)(ee+q)*512 + tid];
            wB[q] = W2[(size_t)(ee+q)*512 + tid + 256];
        }
#pragma unroll
        for (int r = 0; r < 16; ++r) {
            const float4 h4 = *(const float4*)&tls[r*256 + ee];
            a0[r] += h4.x*wA[0] + h4.y*wA[1] + h4.z*wA[2] + h4.w*wA[3];
            a1[r] += h4.x*wB[0] + h4.y*wB[1] + h4.z*wB[2] + h4.w*wB[3];
        }
    }
    {
        const float bA = b2[tid], bB = b2[tid+256];
        const float fA = ffs[tid], fB = ffs[tid+256];
#pragma unroll
        for (int r = 0; r < 16; ++r) {
            a0[r] = (a0[r] + bA) * fA;
            a1[r] = (a1[r] + bB) * fB;
        }
    }
    // L1 norm over d for each (row, i)
#pragma unroll
    for (int r = 0; r < 16; ++r) hls[r*256 + tid] = fabsf(a0[r]);
    __syncthreads();
    {
        const int w = tid >> 6, lane = tid & 63;
#pragma unroll
        for (int rr = 0; rr < 4; ++rr) {
            const int r = w*4 + rr;
            float s = 0.f;
#pragma unroll
            for (int c4 = 0; c4 < 4; ++c4) s += hls[r*256 + lane + c4*64];
            s = wave_reduce_sum(s);
            if (lane == 0) sm0[r] = s;
        }
    }
    __syncthreads();
#pragma unroll
    for (int r = 0; r < 16; ++r) hls[r*256 + tid] = fabsf(a1[r]);
    __syncthreads();
    {
        const int w = tid >> 6, lane = tid & 63;
#pragma unroll
        for (int rr = 0; rr < 4; ++rr) {
            const int r = w*4 + rr;
            float s = 0.f;
#pragma unroll
            for (int c4 = 0; c4 < 4; ++c4) s += hls[r*256 + lane + c4*64];
            s = wave_reduce_sum(s);
            if (lane == 0) sm1[r] = s;
        }
    }
    __syncthreads();
    // write hh[b][i][d=tid][s0..s0+16)
    {
        float* p0 = hh + ((size_t)((b*2+0)*256 + tid)) * S_LEN + s0;
        float* p1 = hh + ((size_t)((b*2+1)*256 + tid)) * S_LEN + s0;
#pragma unroll
        for (int r = 0; r < 16; ++r) {
            p0[r] = a0[r] / (sm0[r] + 1e-8f);
            p1[r] = a1[r] / (sm1[r] + 1e-8f);
        }
    }
}

// ---------------- causal long conv: out[b][d][s] = z[b][d][s] * (1/8192)*sum_{t<=s} x[t]*f[s-t] ----------------
#define CPAD 20
__global__ __launch_bounds__(256, 4) void k_conv(
    const float* __restrict__ xbuf, const int xC, const int xoff,
    const float* __restrict__ hh, const int iord,
    const float* __restrict__ cbuf, float* __restrict__ outb)
{
    const int d = blockIdx.x;
    const int b = blockIdx.y;
    const int tid = threadIdx.x;
    const float* xp = xbuf + ((size_t)(b * xC + xoff + d)) * S_LEN;
    const float* fp = hh   + ((size_t)((b * 2 + iord) * 256 + d)) * S_LEN;
    const float* zp = cbuf + ((size_t)(b * 768 + iord * 256 + d)) * S_LEN;
    float* op = outb + ((size_t)(b * 256 + d)) * S_LEN;

    __shared__ float xs[S_LEN];
    __shared__ float fs[CPAD + S_LEN];
    {
        float4* x4 = (float4*)xs;
        float4* f4 = (float4*)(fs + CPAD);
        const float4* xsrc = (const float4*)xp;
        const float4* fsrc = (const float4*)fp;
        for (int i = tid; i < 1024; i += 256) { x4[i] = xsrc[i]; f4[i] = fsrc[i]; }
        if (tid < CPAD) fs[tid] = 0.f;
    }
    __syncthreads();

    const float4* fs4 = (const float4*)fs;
    const int C0 = tid * 4;
    float acc[4][4];
#pragma unroll
    for (int g = 0; g < 4; ++g)
#pragma unroll
        for (int e = 0; e < 4; ++e) acc[g][e] = 0.f;
    float4 carry[4];
    const int tmax = 3 * 1024 + C0 + 3;
    for (int t0 = 0; t0 <= tmax; t0 += 16) {
        const float4 xa = *(const float4*)&xs[t0];
        const float4 xb = *(const float4*)&xs[t0+4];
        const float4 xc = *(const float4*)&xs[t0+8];
        const float4 xd = *(const float4*)&xs[t0+12];
        const float xv[16] = {xa.x,xa.y,xa.z,xa.w, xb.x,xb.y,xb.z,xb.w,
                              xc.x,xc.y,xc.z,xc.w, xd.x,xd.y,xd.z,xd.w};
#pragma unroll
        for (int g = 0; g < 4; ++g) {
            const int C = g * 1024 + C0;
            if (t0 <= C) {
                const int base4 = (CPAD + C - t0 - 16) >> 2;
                const float4 w0 = fs4[base4];
                const float4 w1 = fs4[base4+1];
                const float4 w2 = fs4[base4+2];
                const float4 w3 = fs4[base4+3];
                const float4 w4 = (t0 == 0) ? fs4[base4+4] : carry[g];
                carry[g] = w0;
                const float w[20] = {w0.x,w0.y,w0.z,w0.w, w1.x,w1.y,w1.z,w1.w,
                                     w2.x,w2.y,w2.z,w2.w, w3.x,w3.y,w3.z,w3.w,
                                     w4.x,w4.y,w4.z,w4.w};
#pragma unroll
                for (int tau = 0; tau < 16; ++tau) {
                    const float xvv = xv[tau];
                    acc[g][0] += xvv * w[16 - tau];
                    acc[g][1] += xvv * w[17 - tau];
                    acc[g][2] += xvv * w[18 - tau];
                    acc[g][3] += xvv * w[19 - tau];
                }
            }
        }
    }
    const float inv = 1.f / 8192.f;
#pragma unroll
    for (int g = 0; g < 4; ++g) {
        const int C = g * 1024 + C0;
        const float4 z4 = *(const float4*)&zp[C];
        float4 r;
        r.x = z4.x * acc[g][0] * inv;
        r.y = z4.y * acc[g][1] * inv;
        r.z = z4.z * acc[g][2] * inv;
        r.w = z4.w * acc[g][3] * inv;
        *(float4*)&op[C] = r;
    }
}

// ---------------- out[b][s][e] = mask * (sum_d v[b][d][s] * W_out[d][e] + b_out[e]) ----------------
__global__ __launch_bounds__(256) void k_out(
    const float* __restrict__ v, const float* __restrict__ Wo,
    const float* __restrict__ bo, const int* __restrict__ pos,
    float* __restrict__ out)
{
    const int b   = blockIdx.y;
    const int s0  = blockIdx.x * 32;
    const int tid = threadIdx.x;
    __shared__ float vs[256 * 36];
    {
        const float4* src = (const float4*)(v + ((size_t)(b*256 + tid)) * S_LEN + s0);
#pragma unroll
        for (int q = 0; q < 8; ++q) {
            *(float4*)&vs[tid*36 + q*4] = src[q];
        }
    }
    __syncthreads();
    float acc[32];
#pragma unroll
    for (int r = 0; r < 32; ++r) acc[r] = 0.f;
    for (int dd = 0; dd < 256; ++dd) {
        const float w = Wo[(size_t)dd * 256 + tid];
        const float* vr = &vs[dd * 36];
#pragma unroll
        for (int q = 0; q < 8; ++q) {
            const float4 x4 = *(const float4*)&vr[q*4];
            acc[q*4+0] += x4.x * w;
            acc[q*4+1] += x4.y * w;
            acc[q*4+2] += x4.z * w;
            acc[q*4+3] += x4.w * w;
        }
    }
    const float bb = bo[tid];
#pragma unroll
    for (int r = 0; r < 32; ++r) {
        const int s = s0 + r;
        const float m = (pos[(size_t)b * S_LEN + s] != -1) ? 1.f : 0.f;
        out[((size_t)b * S_LEN + s) * 256 + tid] = (acc[r] + bb) * m;
    }
}

extern "C" void kernel_launch(void* const* d_in, const int* in_sizes, int n_in,
                              void* d_out, int out_size, void* d_ws, size_t ws_size,
                              hipStream_t stream) {
    const float* emb = (const float*)d_in[0];
    const int*   pos = (const int*)  d_in[1];
    const float* Wp  = (const float*)d_in[2];
    const float* cw  = (const float*)d_in[3];
    const float* cb  = (const float*)d_in[4];
    const float* W1  = (const float*)d_in[5];
    const float* b1  = (const float*)d_in[6];
    const float* lg  = (const float*)d_in[7];
    const float* lb  = (const float*)d_in[8];
    const float* W2  = (const float*)d_in[9];
    const float* b2  = (const float*)d_in[10];
    const float* ffs = (const float*)d_in[11];
    const float* Wo  = (const float*)d_in[12];
    const float* bo  = (const float*)d_in[13];

    float* ws   = (float*)d_ws;
    float* minp = ws + OFF_MINP;
    float* wpt  = ws + OFF_WPT;
    float* weff = ws + OFF_WEFF;
    float* c    = ws + OFF_C;
    float* hh   = ws + OFF_HH;
    float* vb   = ws + OFF_V;
    float* ub   = ws + OFF_U;

    k_minpos<<<dim3(8), dim3(256), 0, stream>>>(pos, minp);
    k_wpt<<<dim3(24, 8), dim3(256), 0, stream>>>(Wp, wpt);
    k_weff<<<dim3(768), dim3(256), 0, stream>>>(wpt, cw, weff);
    k_convgemm<<<dim3(32, 6, 8), dim3(256), 0, stream>>>(emb, pos, weff, cb, c);
    k_ff<<<dim3(256, 8), dim3(256), 0, stream>>>(emb, pos, minp, W1, b1, lg, lb, W2, b2, ffs, hh);
    // v = zs[2]; v = zs[0] * longconv(v, hh[:,0]); v = zs[1] * longconv(v, hh[:,1])
    k_conv<<<dim3(256, 8), dim3(256), 0, stream>>>(c, 768, 512, hh, 0, c, vb);
    k_conv<<<dim3(256, 8), dim3(256), 0, stream>>>(vb, 256, 0, hh, 1, c, ub);
    k_out<<<dim3(128, 8), dim3(256), 0, stream>>>(ub, Wo, bo, pos, (float*)d_out);
}

// Round 3
// 1988.631 us; speedup vs baseline: 1.4601x; 1.4601x over previous
//
#include <hip/hip_runtime.h>
#include <cstdint>

#define S_LEN 4096
#define D_DIM 256

// workspace layout (float offsets)
#define OFF_MINP 0
#define OFF_WPT  16
#define OFF_WEFF (OFF_WPT + 768*256)
#define OFF_C    (OFF_WEFF + 3*256*768)
#define OFF_HH   (OFF_C + 8*768*4096)
#define OFF_V    (OFF_HH + 8*2*256*4096)
#define OFF_U    (OFF_V + 8*256*4096)

__device__ __forceinline__ float wave_reduce_sum(float v) {
#pragma unroll
    for (int off = 32; off > 0; off >>= 1) v += __shfl_down(v, off, 64);
    return v;
}

// ---------------- min valid position per batch ----------------
__global__ __launch_bounds__(256) void k_minpos(const int* __restrict__ pos, float* __restrict__ minp)
{
    const int b = blockIdx.x;
    const int tid = threadIdx.x;
    int mn = 0x7fffffff;
    const int* p = pos + (size_t)b * S_LEN;
    for (int s = tid; s < S_LEN; s += 256) {
        const int v = p[s];
        if (v != -1) mn = min(mn, v);
    }
    __shared__ int red[256];
    red[tid] = mn;
    __syncthreads();
    for (int st = 128; st > 0; st >>= 1) {
        if (tid < st) red[tid] = min(red[tid], red[tid + st]);
        __syncthreads();
    }
    if (tid == 0) minp[b] = (float)red[0];
}

// ---------------- transpose W_proj (256x768) -> WpT (768x256) ----------------
__global__ __launch_bounds__(256) void k_wpt(const float* __restrict__ Wp, float* __restrict__ WpT)
{
    __shared__ float t[32][33];
    const int e0 = blockIdx.x * 32;   // 0..767
    const int d0 = blockIdx.y * 32;   // 0..255
    const int lx = threadIdx.x & 31, ly = threadIdx.x >> 5; // 32x8
#pragma unroll
    for (int q = 0; q < 4; ++q)
        t[ly + 8*q][lx] = Wp[(size_t)(d0 + ly + 8*q) * 768 + e0 + lx];
    __syncthreads();
#pragma unroll
    for (int q = 0; q < 4; ++q)
        WpT[(size_t)(e0 + ly + 8*q) * 256 + d0 + lx] = t[lx][ly + 8*q];
}

// ---------------- Weff[k][d][o] = sum_i WpT[g*256+i][d] * conv_w[o][i][k] ----------------
__global__ __launch_bounds__(256) void k_weff(const float* __restrict__ WpT, const float* __restrict__ cw,
                                              float* __restrict__ weff)
{
    const int o = blockIdx.x;       // 768
    const int d = threadIdx.x;      // 256
    const int g = o >> 8;
    __shared__ float cwrow[768];
    for (int i = threadIdx.x; i < 768; i += 256) cwrow[i] = cw[(size_t)o * 768 + i];
    __syncthreads();
    float a0 = 0.f, a1 = 0.f, a2 = 0.f;
    const float* wb = WpT + (size_t)(g * 256) * 256 + d;
#pragma unroll 4
    for (int i = 0; i < 256; ++i) {
        const float wv = wb[(size_t)i * 256];
        a0 += wv * cwrow[i*3+0];
        a1 += wv * cwrow[i*3+1];
        a2 += wv * cwrow[i*3+2];
    }
    weff[(size_t)(0*256 + d) * 768 + o] = a0;
    weff[(size_t)(1*256 + d) * 768 + o] = a1;
    weff[(size_t)(2*256 + d) * 768 + o] = a2;
}

// ---------------- c[b][o][s] = mask * (conv_b[o] + sum_{k,d} emb[b][s+k-1][d]*Weff[k][d][o]) ----------------
// 128(s) x 128(o) tile per block, fp32 outer-product 8x8 per thread.
__global__ __launch_bounds__(256, 2) void k_convgemm(
    const float* __restrict__ emb, const int* __restrict__ pos,
    const float* __restrict__ weff, const float* __restrict__ convb,
    float* __restrict__ c)
{
    const int b  = blockIdx.z;
    const int o0 = blockIdx.y * 128;
    const int s0 = blockIdx.x * 128;
    const int tid = threadIdx.x;
    __shared__ float Asm[64 * 132];   // [j(d-local)][s] stride 132
    __shared__ float Wsm[64 * 128];   // [j][o]
    const int s_sub = (tid & 15) * 8;
    const int o_sub = (tid >> 4) * 8;
    float acc[8][8];
#pragma unroll
    for (int i = 0; i < 8; ++i)
#pragma unroll
        for (int j = 0; j < 8; ++j) acc[i][j] = 0.f;

    for (int ch = 0; ch < 12; ++ch) {
        const int k  = ch >> 2;
        const int d0 = (ch & 3) * 64;
        // A tile: 128 s-rows x 64 d-cols, stored transposed [d][s]
        {
            const int sl = tid >> 1;          // 0..127
            const int dg = (tid & 1) * 32;    // 0 or 32
            const int rr = s0 + sl + k - 1;
            float4 v[8];
            if (rr >= 0 && rr < S_LEN) {
                const float4* src = (const float4*)(emb + ((size_t)b * S_LEN + rr) * D_DIM + d0 + dg);
#pragma unroll
                for (int q = 0; q < 8; ++q) v[q] = src[q];
            } else {
#pragma unroll
                for (int q = 0; q < 8; ++q) v[q] = make_float4(0.f,0.f,0.f,0.f);
            }
#pragma unroll
            for (int q = 0; q < 8; ++q) {
                Asm[(dg + q*4 + 0) * 132 + sl] = v[q].x;
                Asm[(dg + q*4 + 1) * 132 + sl] = v[q].y;
                Asm[(dg + q*4 + 2) * 132 + sl] = v[q].z;
                Asm[(dg + q*4 + 3) * 132 + sl] = v[q].w;
            }
        }
        // W tile: 64 j-rows x 128 o-cols
        {
            const int j  = tid >> 2;          // 0..63
            const int og = (tid & 3) * 32;    // 0,32,64,96
            const float4* src = (const float4*)(weff + ((size_t)(k * 256 + d0 + j)) * 768 + o0 + og);
            float4* dst = (float4*)&Wsm[j * 128 + og];
#pragma unroll
            for (int q = 0; q < 8; ++q) dst[q] = src[q];
        }
        __syncthreads();
#pragma unroll 4
        for (int j = 0; j < 64; ++j) {
            const float4 a0 = *(const float4*)&Asm[j * 132 + s_sub];
            const float4 a1 = *(const float4*)&Asm[j * 132 + s_sub + 4];
            const float4 w0 = *(const float4*)&Wsm[j * 128 + o_sub];
            const float4 w1 = *(const float4*)&Wsm[j * 128 + o_sub + 4];
            const float av[8] = {a0.x,a0.y,a0.z,a0.w,a1.x,a1.y,a1.z,a1.w};
            const float wv[8] = {w0.x,w0.y,w0.z,w0.w,w1.x,w1.y,w1.z,w1.w};
#pragma unroll
            for (int r = 0; r < 8; ++r)
#pragma unroll
                for (int cc = 0; cc < 8; ++cc) acc[r][cc] += av[r] * wv[cc];
        }
        __syncthreads();
    }
    // epilogue: +bias, *mask, store
    float msk[8];
#pragma unroll
    for (int r = 0; r < 8; ++r)
        msk[r] = (pos[(size_t)b * S_LEN + s0 + s_sub + r] != -1) ? 1.f : 0.f;
#pragma unroll
    for (int cc = 0; cc < 8; ++cc) {
        const int o = o0 + o_sub + cc;
        const float cb = convb[o];
        float* dst = c + ((size_t)(b * 768 + o)) * S_LEN + s0 + s_sub;
        float4 r0, r1;
        r0.x = (acc[0][cc] + cb) * msk[0]; r0.y = (acc[1][cc] + cb) * msk[1];
        r0.z = (acc[2][cc] + cb) * msk[2]; r0.w = (acc[3][cc] + cb) * msk[3];
        r1.x = (acc[4][cc] + cb) * msk[4]; r1.y = (acc[5][cc] + cb) * msk[5];
        r1.z = (acc[6][cc] + cb) * msk[6]; r1.w = (acc[7][cc] + cb) * msk[7];
        *(float4*)dst       = r0;
        *(float4*)(dst + 4) = r1;
    }
}

// ---------------- RoPE + FF + L1-normalize -> hh[b][i][d][s] ----------------
__global__ __launch_bounds__(256) void k_ff(
    const float* __restrict__ emb, const int* __restrict__ pos, const float* __restrict__ minp,
    const float* __restrict__ W1, const float* __restrict__ b1,
    const float* __restrict__ lng, const float* __restrict__ lnb,
    const float* __restrict__ W2, const float* __restrict__ b2,
    const float* __restrict__ ffs, float* __restrict__ hh)
{
    const int b   = blockIdx.y;
    const int s0  = blockIdx.x * 16;
    const int tid = threadIdx.x;
    __shared__ float tls[16 * 256];
    __shared__ float hls[16 * 256];
    __shared__ float mu_s[16], rs_s[16], sm0[16], sm1[16];

    // RoPE: each thread handles row r = tid>>4, 8 pairs starting at (tid&15)*8
    {
        const int r  = tid >> 4;
        const int j0 = (tid & 15) * 8;
        const int s  = s0 + r;
        const int p  = pos[(size_t)b * S_LEN + s];
        const float adj = (p == -1) ? -1.f : ((float)p - minp[b]);
        const float4* src = (const float4*)(emb + ((size_t)b * S_LEN + s) * D_DIM + j0 * 2);
        const float4 q0 = src[0], q1 = src[1], q2 = src[2], q3 = src[3];
        const float ev[16] = {q0.x,q0.y,q0.z,q0.w,q1.x,q1.y,q1.z,q1.w,
                              q2.x,q2.y,q2.z,q2.w,q3.x,q3.y,q3.z,q3.w};
        float* dst = &tls[r * 256 + j0 * 2];
#pragma unroll
        for (int jj = 0; jj < 8; ++jj) {
            const int j = j0 + jj;
            const float theta = expf(-(float)j * 0.07195578415606394f); // ln(10000)/128
            float sn, cs;
            sincosf(adj * theta, &sn, &cs);
            const float x1 = ev[2*jj], x2 = ev[2*jj+1];
            dst[2*jj]   = x1 * cs - x2 * sn;
            dst[2*jj+1] = x1 * sn + x2 * cs;
        }
    }
    __syncthreads();
    // h1 = t @ W1 + b1 ; col = tid, 16 rows
    float h1a[16];
#pragma unroll
    for (int r = 0; r < 16; ++r) h1a[r] = 0.f;
    for (int dd = 0; dd < 256; dd += 4) {
        const float w0 = W1[(size_t)(dd+0)*256 + tid];
        const float w1 = W1[(size_t)(dd+1)*256 + tid];
        const float w2 = W1[(size_t)(dd+2)*256 + tid];
        const float w3 = W1[(size_t)(dd+3)*256 + tid];
#pragma unroll
        for (int r = 0; r < 16; ++r) {
            const float4 t4 = *(const float4*)&tls[r*256 + dd];
            h1a[r] += t4.x*w0 + t4.y*w1 + t4.z*w2 + t4.w*w3;
        }
    }
    {
        const float bb = b1[tid];
#pragma unroll
        for (int r = 0; r < 16; ++r) hls[r*256 + tid] = h1a[r] + bb;
    }
    __syncthreads();
    // LayerNorm stats (4 rows per wave)
    {
        const int w = tid >> 6, lane = tid & 63;
#pragma unroll
        for (int rr = 0; rr < 4; ++rr) {
            const int r = w * 4 + rr;
            float s = 0.f, q = 0.f;
#pragma unroll
            for (int c4 = 0; c4 < 4; ++c4) {
                const float v = hls[r*256 + lane + c4*64];
                s += v; q += v*v;
            }
            s = wave_reduce_sum(s);
            q = wave_reduce_sum(q);
            if (lane == 0) {
                const float mu = s * (1.f/256.f);
                const float var = q * (1.f/256.f) - mu*mu;
                mu_s[r] = mu;
                rs_s[r] = rsqrtf(var + 1e-5f);
            }
        }
    }
    __syncthreads();
    // LN apply + exact gelu -> tls
    {
        const float g = lng[tid], be = lnb[tid];
#pragma unroll
        for (int r = 0; r < 16; ++r) {
            const float h = (hls[r*256 + tid] - mu_s[r]) * rs_s[r] * g + be;
            tls[r*256 + tid] = 0.5f * h * (1.f + erff(h * 0.7071067811865475f));
        }
    }
    __syncthreads();
    // h2 = gelu(h) @ W2 + b2, cols tid and tid+256
    float a0[16], a1[16];
#pragma unroll
    for (int r = 0; r < 16; ++r) { a0[r] = 0.f; a1[r] = 0.f; }
    for (int ee = 0; ee < 256; ee += 4) {
        float wA[4], wB[4];
#pragma unroll
        for (int q = 0; q < 4; ++q) {
            wA[q] = W2[(size_t)(ee+q)*512 + tid];
            wB[q] = W2[(size_t)(ee+q)*512 + tid + 256];
        }
#pragma unroll
        for (int r = 0; r < 16; ++r) {
            const float4 h4 = *(const float4*)&tls[r*256 + ee];
            a0[r] += h4.x*wA[0] + h4.y*wA[1] + h4.z*wA[2] + h4.w*wA[3];
            a1[r] += h4.x*wB[0] + h4.y*wB[1] + h4.z*wB[2] + h4.w*wB[3];
        }
    }
    {
        const float bA = b2[tid], bB = b2[tid+256];
        const float fA = ffs[tid], fB = ffs[tid+256];
#pragma unroll
        for (int r = 0; r < 16; ++r) {
            a0[r] = (a0[r] + bA) * fA;
            a1[r] = (a1[r] + bB) * fB;
        }
    }
    // L1 norm over d for each (row, i)
#pragma unroll
    for (int r = 0; r < 16; ++r) hls[r*256 + tid] = fabsf(a0[r]);
    __syncthreads();
    {
        const int w = tid >> 6, lane = tid & 63;
#pragma unroll
        for (int rr = 0; rr < 4; ++rr) {
            const int r = w*4 + rr;
            float s = 0.f;
#pragma unroll
            for (int c4 = 0; c4 < 4; ++c4) s += hls[r*256 + lane + c4*64];
            s = wave_reduce_sum(s);
            if (lane == 0) sm0[r] = s;
        }
    }
    __syncthreads();
#pragma unroll
    for (int r = 0; r < 16; ++r) hls[r*256 + tid] = fabsf(a1[r]);
    __syncthreads();
    {
        const int w = tid >> 6, lane = tid & 63;
#pragma unroll
        for (int rr = 0; rr < 4; ++rr) {
            const int r = w*4 + rr;
            float s = 0.f;
#pragma unroll
            for (int c4 = 0; c4 < 4; ++c4) s += hls[r*256 + lane + c4*64];
            s = wave_reduce_sum(s);
            if (lane == 0) sm1[r] = s;
        }
    }
    __syncthreads();
    // write hh[b][i][d=tid][s0..s0+16)
    {
        float* p0 = hh + ((size_t)((b*2+0)*256 + tid)) * S_LEN + s0;
        float* p1 = hh + ((size_t)((b*2+1)*256 + tid)) * S_LEN + s0;
#pragma unroll
        for (int r = 0; r < 16; ++r) {
            p0[r] = a0[r] / (sm0[r] + 1e-8f);
            p1[r] = a1[r] / (sm1[r] + 1e-8f);
        }
    }
}

// ---------------- causal long conv: out[b][d][s] = z[b][d][s] * (1/8192)*sum_{t<=s} x[t]*f[s-t] ----------------
// Thread tid computes 8 consecutive outputs in each of 2 groups: C0 = tid*8, C1 = 2048 + tid*8.
// f is stored in LDS in an even/odd-float4-split swizzled layout so that the per-lane
// window loads (lane stride 8 floats = 2 float4) become lane-stride-1 float4 reads
// (conflict-free). 8 ds_read_b128 per 256 FMAs (was 16).
#define FPAD 24            // zero floats in front of f (covers tau down to -22)
#define NF4  1030          // (FPAD + 4096)/4 float4s
#define SWZ(i) (((i) >> 1) + ((i) & 1) * 515)
__global__ __launch_bounds__(256, 4) void k_conv(
    const float* __restrict__ xbuf, const int xC, const int xoff,
    const float* __restrict__ hh, const int iord,
    const float* __restrict__ cbuf, float* __restrict__ outb)
{
    const int d = blockIdx.x;
    const int b = blockIdx.y;
    const int tid = threadIdx.x;
    const float* xp = xbuf + ((size_t)(b * xC + xoff + d)) * S_LEN;
    const float* fp = hh   + ((size_t)((b * 2 + iord) * 256 + d)) * S_LEN;
    const float* zp = cbuf + ((size_t)(b * 768 + iord * 256 + d)) * S_LEN;
    float* op = outb + ((size_t)(b * 256 + d)) * S_LEN;

    __shared__ float  xs[S_LEN];
    __shared__ float4 fs4[NF4];
    {
        float4* x4 = (float4*)xs;
        const float4* xsrc = (const float4*)xp;
        const float4* fsrc = (const float4*)fp;
        for (int i = tid; i < 1024; i += 256) x4[i] = xsrc[i];
        for (int i = tid; i < NF4; i += 256) {
            float4 v = (i < 6) ? make_float4(0.f, 0.f, 0.f, 0.f) : fsrc[i - 6];
            fs4[SWZ(i)] = v;
        }
    }
    __syncthreads();

    const int C0 = tid * 8;            // group0 outputs [C0, C0+7]
    // f windows in registers: fa/fb hold f[W .. W+23], W = Cg - t0 - 16
    float fa[24], fb[24];
    float accA[8], accB[8];
#pragma unroll
    for (int e = 0; e < 8; ++e) { accA[e] = 0.f; accB[e] = 0.f; }

    const float4* xs4 = (const float4*)xs;
    const int tmax = 2048 + C0 + 7;
    for (int t0 = 0; t0 <= tmax; t0 += 16) {
        // x[t0..t0+15], wave-uniform broadcast reads
        const float4 xa = xs4[(t0 >> 2) + 0];
        const float4 xb = xs4[(t0 >> 2) + 1];
        const float4 xc = xs4[(t0 >> 2) + 2];
        const float4 xd = xs4[(t0 >> 2) + 3];
        const float xv[16] = {xa.x,xa.y,xa.z,xa.w, xb.x,xb.y,xb.z,xb.w,
                              xc.x,xc.y,xc.z,xc.w, xd.x,xd.y,xd.z,xd.w};
        const bool g0 = (t0 <= C0 + 7);
        if (g0) {
            const int ib = (8 + C0 - t0) >> 2;   // float4 index of window base (pre-swizzle, incl FPAD)
            if (t0 == 0) {
                const float4 w4 = fs4[SWZ(ib + 4)];
                const float4 w5 = fs4[SWZ(ib + 5)];
                fa[16]=w4.x; fa[17]=w4.y; fa[18]=w4.z; fa[19]=w4.w;
                fa[20]=w5.x; fa[21]=w5.y; fa[22]=w5.z; fa[23]=w5.w;
            } else {
#pragma unroll
                for (int q = 0; q < 8; ++q) fa[16 + q] = fa[q];
            }
            const float4 w0 = fs4[SWZ(ib + 0)];
            const float4 w1 = fs4[SWZ(ib + 1)];
            const float4 w2 = fs4[SWZ(ib + 2)];
            const float4 w3 = fs4[SWZ(ib + 3)];
            fa[0]=w0.x; fa[1]=w0.y; fa[2]=w0.z; fa[3]=w0.w;
            fa[4]=w1.x; fa[5]=w1.y; fa[6]=w1.z; fa[7]=w1.w;
            fa[8]=w2.x; fa[9]=w2.y; fa[10]=w2.z; fa[11]=w2.w;
            fa[12]=w3.x; fa[13]=w3.y; fa[14]=w3.z; fa[15]=w3.w;
#pragma unroll
            for (int j = 0; j < 16; ++j) {
                const float xj = xv[j];
#pragma unroll
                for (int e = 0; e < 8; ++e) accA[e] += xj * fa[16 + e - j];
            }
        }
        // group 1 (always active within loop bound)
        {
            const int ib = (8 + 2048 + C0 - t0) >> 2;
            if (t0 == 0) {
                const float4 w4 = fs4[SWZ(ib + 4)];
                const float4 w5 = fs4[SWZ(ib + 5)];
                fb[16]=w4.x; fb[17]=w4.y; fb[18]=w4.z; fb[19]=w4.w;
                fb[20]=w5.x; fb[21]=w5.y; fb[22]=w5.z; fb[23]=w5.w;
            } else {
#pragma unroll
                for (int q = 0; q < 8; ++q) fb[16 + q] = fb[q];
            }
            const float4 w0 = fs4[SWZ(ib + 0)];
            const float4 w1 = fs4[SWZ(ib + 1)];
            const float4 w2 = fs4[SWZ(ib + 2)];
            const float4 w3 = fs4[SWZ(ib + 3)];
            fb[0]=w0.x; fb[1]=w0.y; fb[2]=w0.z; fb[3]=w0.w;
            fb[4]=w1.x; fb[5]=w1.y; fb[6]=w1.z; fb[7]=w1.w;
            fb[8]=w2.x; fb[9]=w2.y; fb[10]=w2.z; fb[11]=w2.w;
            fb[12]=w3.x; fb[13]=w3.y; fb[14]=w3.z; fb[15]=w3.w;
#pragma unroll
            for (int j = 0; j < 16; ++j) {
                const float xj = xv[j];
#pragma unroll
                for (int e = 0; e < 8; ++e) accB[e] += xj * fb[16 + e - j];
            }
        }
    }

    const float inv = 1.f / 8192.f;
    {
        const float4 z0 = *(const float4*)&zp[C0];
        const float4 z1 = *(const float4*)&zp[C0 + 4];
        float4 r0, r1;
        r0.x = z0.x * accA[0] * inv; r0.y = z0.y * accA[1] * inv;
        r0.z = z0.z * accA[2] * inv; r0.w = z0.w * accA[3] * inv;
        r1.x = z1.x * accA[4] * inv; r1.y = z1.y * accA[5] * inv;
        r1.z = z1.z * accA[6] * inv; r1.w = z1.w * accA[7] * inv;
        *(float4*)&op[C0]     = r0;
        *(float4*)&op[C0 + 4] = r1;
    }
    {
        const int C1 = 2048 + C0;
        const float4 z0 = *(const float4*)&zp[C1];
        const float4 z1 = *(const float4*)&zp[C1 + 4];
        float4 r0, r1;
        r0.x = z0.x * accB[0] * inv; r0.y = z0.y * accB[1] * inv;
        r0.z = z0.z * accB[2] * inv; r0.w = z0.w * accB[3] * inv;
        r1.x = z1.x * accB[4] * inv; r1.y = z1.y * accB[5] * inv;
        r1.z = z1.z * accB[6] * inv; r1.w = z1.w * accB[7] * inv;
        *(float4*)&op[C1]     = r0;
        *(float4*)&op[C1 + 4] = r1;
    }
}

// ---------------- out[b][s][e] = mask * (sum_d v[b][d][s] * W_out[d][e] + b_out[e]) ----------------
__global__ __launch_bounds__(256) void k_out(
    const float* __restrict__ v, const float* __restrict__ Wo,
    const float* __restrict__ bo, const int* __restrict__ pos,
    float* __restrict__ out)
{
    const int b   = blockIdx.y;
    const int s0  = blockIdx.x * 32;
    const int tid = threadIdx.x;
    __shared__ float vs[256 * 36];
    {
        const float4* src = (const float4*)(v + ((size_t)(b*256 + tid)) * S_LEN + s0);
#pragma unroll
        for (int q = 0; q < 8; ++q) {
            *(float4*)&vs[tid*36 + q*4] = src[q];
        }
    }
    __syncthreads();
    float acc[32];
#pragma unroll
    for (int r = 0; r < 32; ++r) acc[r] = 0.f;
    for (int dd = 0; dd < 256; ++dd) {
        const float w = Wo[(size_t)dd * 256 + tid];
        const float* vr = &vs[dd * 36];
#pragma unroll
        for (int q = 0; q < 8; ++q) {
            const float4 x4 = *(const float4*)&vr[q*4];
            acc[q*4+0] += x4.x * w;
            acc[q*4+1] += x4.y * w;
            acc[q*4+2] += x4.z * w;
            acc[q*4+3] += x4.w * w;
        }
    }
    const float bb = bo[tid];
#pragma unroll
    for (int r = 0; r < 32; ++r) {
        const int s = s0 + r;
        const float m = (pos[(size_t)b * S_LEN + s] != -1) ? 1.f : 0.f;
        out[((size_t)b * S_LEN + s) * 256 + tid] = (acc[r] + bb) * m;
    }
}

extern "C" void kernel_launch(void* const* d_in, const int* in_sizes, int n_in,
                              void* d_out, int out_size, void* d_ws, size_t ws_size,
                              hipStream_t stream) {
    const float* emb = (const float*)d_in[0];
    const int*   pos = (const int*)  d_in[1];
    const float* Wp  = (const float*)d_in[2];
    const float* cw  = (const float*)d_in[3];
    const float* cb  = (const float*)d_in[4];
    const float* W1  = (const float*)d_in[5];
    const float* b1  = (const float*)d_in[6];
    const float* lg  = (const float*)d_in[7];
    const float* lb  = (const float*)d_in[8];
    const float* W2  = (const float*)d_in[9];
    const float* b2  = (const float*)d_in[10];
    const float* ffs = (const float*)d_in[11];
    const float* Wo  = (const float*)d_in[12];
    const float* bo  = (const float*)d_in[13];

    float* ws   = (float*)d_ws;
    float* minp = ws + OFF_MINP;
    float* wpt  = ws + OFF_WPT;
    float* weff = ws + OFF_WEFF;
    float* c    = ws + OFF_C;
    float* hh   = ws + OFF_HH;
    float* vb   = ws + OFF_V;
    float* ub   = ws + OFF_U;

    k_minpos<<<dim3(8), dim3(256), 0, stream>>>(pos, minp);
    k_wpt<<<dim3(24, 8), dim3(256), 0, stream>>>(Wp, wpt);
    k_weff<<<dim3(768), dim3(256), 0, stream>>>(wpt, cw, weff);
    k_convgemm<<<dim3(32, 6, 8), dim3(256), 0, stream>>>(emb, pos, weff, cb, c);
    k_ff<<<dim3(256, 8), dim3(256), 0, stream>>>(emb, pos, minp, W1, b1, lg, lb, W2, b2, ffs, hh);
    // v = zs[2]; v = zs[0] * longconv(v, hh[:,0]); v = zs[1] * longconv(v, hh[:,1])
    k_conv<<<dim3(256, 8), dim3(256), 0, stream>>>(c, 768, 512, hh, 0, c, vb);
    k_conv<<<dim3(256, 8), dim3(256), 0, stream>>>(vb, 256, 0, hh, 1, c, ub);
    k_out<<<dim3(128, 8), dim3(256), 0, stream>>>(ub, Wo, bo, pos, (float*)d_out);
}

// Round 4
// 1096.269 us; speedup vs baseline: 2.6486x; 1.8140x over previous
//
#include <hip/hip_runtime.h>
#include <cstdint>

#define S_LEN 4096
#define D_DIM 256

// workspace layout (float offsets)
#define OFF_MINP 0
#define OFF_WPT  16
#define OFF_WEFF (OFF_WPT + 768*256)
#define OFF_C    (OFF_WEFF + 3*256*768)
#define OFF_HH   (OFF_C + 8*768*4096)
#define OFF_V    (OFF_HH + 8*2*256*4096)
#define OFF_U    (OFF_V + 8*256*4096)

typedef __attribute__((ext_vector_type(8))) short short8;
typedef __attribute__((ext_vector_type(4))) float f32x4;

__device__ __forceinline__ float wave_reduce_sum(float v) {
#pragma unroll
    for (int off = 32; off > 0; off >>= 1) v += __shfl_down(v, off, 64);
    return v;
}

__device__ __forceinline__ unsigned int f2bf(float x) {
    union { float f; unsigned int u; } v; v.f = x;
    unsigned int r = v.u + 0x7fffu + ((v.u >> 16) & 1u);   // RNE
    return r >> 16;
}

// ---------------- min valid position per batch ----------------
__global__ __launch_bounds__(256) void k_minpos(const int* __restrict__ pos, float* __restrict__ minp)
{
    const int b = blockIdx.x;
    const int tid = threadIdx.x;
    int mn = 0x7fffffff;
    const int* p = pos + (size_t)b * S_LEN;
    for (int s = tid; s < S_LEN; s += 256) {
        const int v = p[s];
        if (v != -1) mn = min(mn, v);
    }
    __shared__ int red[256];
    red[tid] = mn;
    __syncthreads();
    for (int st = 128; st > 0; st >>= 1) {
        if (tid < st) red[tid] = min(red[tid], red[tid + st]);
        __syncthreads();
    }
    if (tid == 0) minp[b] = (float)red[0];
}

// ---------------- transpose W_proj (256x768) -> WpT (768x256) ----------------
__global__ __launch_bounds__(256) void k_wpt(const float* __restrict__ Wp, float* __restrict__ WpT)
{
    __shared__ float t[32][33];
    const int e0 = blockIdx.x * 32;   // 0..767
    const int d0 = blockIdx.y * 32;   // 0..255
    const int lx = threadIdx.x & 31, ly = threadIdx.x >> 5; // 32x8
#pragma unroll
    for (int q = 0; q < 4; ++q)
        t[ly + 8*q][lx] = Wp[(size_t)(d0 + ly + 8*q) * 768 + e0 + lx];
    __syncthreads();
#pragma unroll
    for (int q = 0; q < 4; ++q)
        WpT[(size_t)(e0 + ly + 8*q) * 256 + d0 + lx] = t[lx][ly + 8*q];
}

// ---------------- Weff[k][d][o] = sum_i WpT[g*256+i][d] * conv_w[o][i][k] ----------------
__global__ __launch_bounds__(256) void k_weff(const float* __restrict__ WpT, const float* __restrict__ cw,
                                              float* __restrict__ weff)
{
    const int o = blockIdx.x;       // 768
    const int d = threadIdx.x;      // 256
    const int g = o >> 8;
    __shared__ float cwrow[768];
    for (int i = threadIdx.x; i < 768; i += 256) cwrow[i] = cw[(size_t)o * 768 + i];
    __syncthreads();
    float a0 = 0.f, a1 = 0.f, a2 = 0.f;
    const float* wb = WpT + (size_t)(g * 256) * 256 + d;
#pragma unroll 4
    for (int i = 0; i < 256; ++i) {
        const float wv = wb[(size_t)i * 256];
        a0 += wv * cwrow[i*3+0];
        a1 += wv * cwrow[i*3+1];
        a2 += wv * cwrow[i*3+2];
    }
    weff[(size_t)(0*256 + d) * 768 + o] = a0;
    weff[(size_t)(1*256 + d) * 768 + o] = a1;
    weff[(size_t)(2*256 + d) * 768 + o] = a2;
}

// ---------------- c[b][o][s] = mask * (conv_b[o] + sum_{k,d} emb[b][s+k-1][d]*Weff[k][d][o]) ----------------
__global__ __launch_bounds__(256, 2) void k_convgemm(
    const float* __restrict__ emb, const int* __restrict__ pos,
    const float* __restrict__ weff, const float* __restrict__ convb,
    float* __restrict__ c)
{
    const int b  = blockIdx.z;
    const int o0 = blockIdx.y * 128;
    const int s0 = blockIdx.x * 128;
    const int tid = threadIdx.x;
    __shared__ float Asm[64 * 132];   // [j(d-local)][s] stride 132
    __shared__ float Wsm[64 * 128];   // [j][o]
    const int s_sub = (tid & 15) * 8;
    const int o_sub = (tid >> 4) * 8;
    float acc[8][8];
#pragma unroll
    for (int i = 0; i < 8; ++i)
#pragma unroll
        for (int j = 0; j < 8; ++j) acc[i][j] = 0.f;

    for (int ch = 0; ch < 12; ++ch) {
        const int k  = ch >> 2;
        const int d0 = (ch & 3) * 64;
        {
            const int sl = tid >> 1;
            const int dg = (tid & 1) * 32;
            const int rr = s0 + sl + k - 1;
            float4 v[8];
            if (rr >= 0 && rr < S_LEN) {
                const float4* src = (const float4*)(emb + ((size_t)b * S_LEN + rr) * D_DIM + d0 + dg);
#pragma unroll
                for (int q = 0; q < 8; ++q) v[q] = src[q];
            } else {
#pragma unroll
                for (int q = 0; q < 8; ++q) v[q] = make_float4(0.f,0.f,0.f,0.f);
            }
#pragma unroll
            for (int q = 0; q < 8; ++q) {
                Asm[(dg + q*4 + 0) * 132 + sl] = v[q].x;
                Asm[(dg + q*4 + 1) * 132 + sl] = v[q].y;
                Asm[(dg + q*4 + 2) * 132 + sl] = v[q].z;
                Asm[(dg + q*4 + 3) * 132 + sl] = v[q].w;
            }
        }
        {
            const int j  = tid >> 2;
            const int og = (tid & 3) * 32;
            const float4* src = (const float4*)(weff + ((size_t)(k * 256 + d0 + j)) * 768 + o0 + og);
            float4* dst = (float4*)&Wsm[j * 128 + og];
#pragma unroll
            for (int q = 0; q < 8; ++q) dst[q] = src[q];
        }
        __syncthreads();
#pragma unroll 4
        for (int j = 0; j < 64; ++j) {
            const float4 a0 = *(const float4*)&Asm[j * 132 + s_sub];
            const float4 a1 = *(const float4*)&Asm[j * 132 + s_sub + 4];
            const float4 w0 = *(const float4*)&Wsm[j * 128 + o_sub];
            const float4 w1 = *(const float4*)&Wsm[j * 128 + o_sub + 4];
            const float av[8] = {a0.x,a0.y,a0.z,a0.w,a1.x,a1.y,a1.z,a1.w};
            const float wv[8] = {w0.x,w0.y,w0.z,w0.w,w1.x,w1.y,w1.z,w1.w};
#pragma unroll
            for (int r = 0; r < 8; ++r)
#pragma unroll
                for (int cc = 0; cc < 8; ++cc) acc[r][cc] += av[r] * wv[cc];
        }
        __syncthreads();
    }
    float msk[8];
#pragma unroll
    for (int r = 0; r < 8; ++r)
        msk[r] = (pos[(size_t)b * S_LEN + s0 + s_sub + r] != -1) ? 1.f : 0.f;
#pragma unroll
    for (int cc = 0; cc < 8; ++cc) {
        const int o = o0 + o_sub + cc;
        const float cb = convb[o];
        float* dst = c + ((size_t)(b * 768 + o)) * S_LEN + s0 + s_sub;
        float4 r0, r1;
        r0.x = (acc[0][cc] + cb) * msk[0]; r0.y = (acc[1][cc] + cb) * msk[1];
        r0.z = (acc[2][cc] + cb) * msk[2]; r0.w = (acc[3][cc] + cb) * msk[3];
        r1.x = (acc[4][cc] + cb) * msk[4]; r1.y = (acc[5][cc] + cb) * msk[5];
        r1.z = (acc[6][cc] + cb) * msk[6]; r1.w = (acc[7][cc] + cb) * msk[7];
        *(float4*)dst       = r0;
        *(float4*)(dst + 4) = r1;
    }
}

// ---------------- RoPE + FF + L1-normalize -> hh[b][i][d][s] ----------------
__global__ __launch_bounds__(256) void k_ff(
    const float* __restrict__ emb, const int* __restrict__ pos, const float* __restrict__ minp,
    const float* __restrict__ W1, const float* __restrict__ b1,
    const float* __restrict__ lng, const float* __restrict__ lnb,
    const float* __restrict__ W2, const float* __restrict__ b2,
    const float* __restrict__ ffs, float* __restrict__ hh)
{
    const int b   = blockIdx.y;
    const int s0  = blockIdx.x * 16;
    const int tid = threadIdx.x;
    __shared__ float tls[16 * 256];
    __shared__ float hls[16 * 256];
    __shared__ float mu_s[16], rs_s[16], sm0[16], sm1[16];
    {
        const int r  = tid >> 4;
        const int j0 = (tid & 15) * 8;
        const int s  = s0 + r;
        const int p  = pos[(size_t)b * S_LEN + s];
        const float adj = (p == -1) ? -1.f : ((float)p - minp[b]);
        const float4* src = (const float4*)(emb + ((size_t)b * S_LEN + s) * D_DIM + j0 * 2);
        const float4 q0 = src[0], q1 = src[1], q2 = src[2], q3 = src[3];
        const float ev[16] = {q0.x,q0.y,q0.z,q0.w,q1.x,q1.y,q1.z,q1.w,
                              q2.x,q2.y,q2.z,q2.w,q3.x,q3.y,q3.z,q3.w};
        float* dst = &tls[r * 256 + j0 * 2];
#pragma unroll
        for (int jj = 0; jj < 8; ++jj) {
            const int j = j0 + jj;
            const float theta = expf(-(float)j * 0.07195578415606394f);
            float sn, cs;
            sincosf(adj * theta, &sn, &cs);
            const float x1 = ev[2*jj], x2 = ev[2*jj+1];
            dst[2*jj]   = x1 * cs - x2 * sn;
            dst[2*jj+1] = x1 * sn + x2 * cs;
        }
    }
    __syncthreads();
    float h1a[16];
#pragma unroll
    for (int r = 0; r < 16; ++r) h1a[r] = 0.f;
    for (int dd = 0; dd < 256; dd += 4) {
        const float w0 = W1[(size_t)(dd+0)*256 + tid];
        const float w1 = W1[(size_t)(dd+1)*256 + tid];
        const float w2 = W1[(size_t)(dd+2)*256 + tid];
        const float w3 = W1[(size_t)(dd+3)*256 + tid];
#pragma unroll
        for (int r = 0; r < 16; ++r) {
            const float4 t4 = *(const float4*)&tls[r*256 + dd];
            h1a[r] += t4.x*w0 + t4.y*w1 + t4.z*w2 + t4.w*w3;
        }
    }
    {
        const float bb = b1[tid];
#pragma unroll
        for (int r = 0; r < 16; ++r) hls[r*256 + tid] = h1a[r] + bb;
    }
    __syncthreads();
    {
        const int w = tid >> 6, lane = tid & 63;
#pragma unroll
        for (int rr = 0; rr < 4; ++rr) {
            const int r = w * 4 + rr;
            float s = 0.f, q = 0.f;
#pragma unroll
            for (int c4 = 0; c4 < 4; ++c4) {
                const float v = hls[r*256 + lane + c4*64];
                s += v; q += v*v;
            }
            s = wave_reduce_sum(s);
            q = wave_reduce_sum(q);
            if (lane == 0) {
                const float mu = s * (1.f/256.f);
                const float var = q * (1.f/256.f) - mu*mu;
                mu_s[r] = mu;
                rs_s[r] = rsqrtf(var + 1e-5f);
            }
        }
    }
    __syncthreads();
    {
        const float g = lng[tid], be = lnb[tid];
#pragma unroll
        for (int r = 0; r < 16; ++r) {
            const float h = (hls[r*256 + tid] - mu_s[r]) * rs_s[r] * g + be;
            tls[r*256 + tid] = 0.5f * h * (1.f + erff(h * 0.7071067811865475f));
        }
    }
    __syncthreads();
    float a0[16], a1[16];
#pragma unroll
    for (int r = 0; r < 16; ++r) { a0[r] = 0.f; a1[r] = 0.f; }
    for (int ee = 0; ee < 256; ee += 4) {
        float wA[4], wB[4];
#pragma unroll
        for (int q = 0; q < 4; ++q) {
            wA[q] = W2[(size_t)(ee+q)*512 + tid];
            wB[q] = W2[(size_t)(ee+q)*512 + tid + 256];
        }
#pragma unroll
        for (int r = 0; r < 16; ++r) {
            const float4 h4 = *(const float4*)&tls[r*256 + ee];
            a0[r] += h4.x*wA[0] + h4.y*wA[1] + h4.z*wA[2] + h4.w*wA[3];
            a1[r] += h4.x*wB[0] + h4.y*wB[1] + h4.z*wB[2] + h4.w*wB[3];
        }
    }
    {
        const float bA = b2[tid], bB = b2[tid+256];
        const float fA = ffs[tid], fB = ffs[tid+256];
#pragma unroll
        for (int r = 0; r < 16; ++r) {
            a0[r] = (a0[r] + bA) * fA;
            a1[r] = (a1[r] + bB) * fB;
        }
    }
#pragma unroll
    for (int r = 0; r < 16; ++r) hls[r*256 + tid] = fabsf(a0[r]);
    __syncthreads();
    {
        const int w = tid >> 6, lane = tid & 63;
#pragma unroll
        for (int rr = 0; rr < 4; ++rr) {
            const int r = w*4 + rr;
            float s = 0.f;
#pragma unroll
            for (int c4 = 0; c4 < 4; ++c4) s += hls[r*256 + lane + c4*64];
            s = wave_reduce_sum(s);
            if (lane == 0) sm0[r] = s;
        }
    }
    __syncthreads();
#pragma unroll
    for (int r = 0; r < 16; ++r) hls[r*256 + tid] = fabsf(a1[r]);
    __syncthreads();
    {
        const int w = tid >> 6, lane = tid & 63;
#pragma unroll
        for (int rr = 0; rr < 4; ++rr) {
            const int r = w*4 + rr;
            float s = 0.f;
#pragma unroll
            for (int c4 = 0; c4 < 4; ++c4) s += hls[r*256 + lane + c4*64];
            s = wave_reduce_sum(s);
            if (lane == 0) sm1[r] = s;
        }
    }
    __syncthreads();
    {
        float* p0 = hh + ((size_t)((b*2+0)*256 + tid)) * S_LEN + s0;
        float* p1 = hh + ((size_t)((b*2+1)*256 + tid)) * S_LEN + s0;
#pragma unroll
        for (int r = 0; r < 16; ++r) {
            p0[r] = a0[r] / (sm0[r] + 1e-8f);
            p1[r] = a1[r] / (sm1[r] + 1e-8f);
        }
    }
}

// ---------------- MFMA blocked-Toeplitz causal long conv ----------------
// out[64p+q] = z[..] * (1/8192) * sum_{r,v} f[64r+q-v] * x[64(p-r)+v]
// Per block: one (b,d) channel, 1 wave (64 threads).
// A = G_r (Toeplitz from f): A[m=lane&15][k=quad*8+j] = fr[4095-64r-q+v] (fr = reversed f,
//   top-padded with zeros); read via pair-duplicated frx[i]=(fr[i],fr[i+1]) as 4 dwords.
// B = X: B[k=v][n=p] = x[64(p-r)+v]; bf16 x with 960-elem zero front pad (handles p<r),
//   stored xor-block-swizzled (16B blocks: phys = blk ^ ((blk>>3)&7)) for bank spread.
// C/D: col(p)=lane&15, row(q)=(lane>>4)*4+reg  [guide §3, m89/m91 verified]
#define XS_PAD   960
#define XS_ELEMS 5056     // 960 + 4096 = 632 16B-blocks
#define FRX_WORDS 4160
__device__ __forceinline__ int xsw(int blk) { return blk ^ ((blk >> 3) & 7); }

__global__ __launch_bounds__(64) void k_conv_mfma(
    const float* __restrict__ xbuf, const int xC, const int xoff,
    const float* __restrict__ hh, const int iord,
    const float* __restrict__ cbuf, float* __restrict__ outb)
{
    const int d = blockIdx.x;
    const int b = blockIdx.y;
    const int lane = threadIdx.x;      // 0..63
    const float* xp = xbuf + ((size_t)(b * xC + xoff + d)) * S_LEN;
    const float* fp = hh   + ((size_t)((b * 2 + iord) * 256 + d)) * S_LEN;
    const float* zp = cbuf + ((size_t)(b * 768 + iord * 256 + d)) * S_LEN;
    float* op = outb + ((size_t)(b * 256 + d)) * S_LEN;

    __shared__ unsigned short xs[XS_ELEMS];
    __shared__ unsigned int   frx[FRX_WORDS];

    // ---- stage x -> bf16, swizzled blocks ----
    {
        // zero front pad: blocks 0..119
        for (int blk = lane; blk < 120; blk += 64) {
            int4 z; z.x = 0; z.y = 0; z.z = 0; z.w = 0;
            *(int4*)(xs + xsw(blk) * 8) = z;
        }
#pragma unroll
        for (int it = 0; it < 8; ++it) {
            const int idx = it * 64 + lane;          // block within x: 0..511
            const int j = idx * 8;
            const float4 v0 = *(const float4*)(xp + j);
            const float4 v1 = *(const float4*)(xp + j + 4);
            int4 w;
            w.x = (int)(f2bf(v0.x) | (f2bf(v0.y) << 16));
            w.y = (int)(f2bf(v0.z) | (f2bf(v0.w) << 16));
            w.z = (int)(f2bf(v1.x) | (f2bf(v1.y) << 16));
            w.w = (int)(f2bf(v1.z) | (f2bf(v1.w) << 16));
            *(int4*)(xs + xsw(120 + idx) * 8) = w;
        }
    }
    // ---- stage frx: frx[i] = bf16(fr[i]) | bf16(fr[i+1])<<16, fr[i] = f[4095-i], fr[>=4096]=0 ----
    {
        frx[4096 + lane] = 0u;                       // top pad 4096..4159
        if (lane == 0) frx[4095] = f2bf(fp[0]);      // (f[0], 0)
#pragma unroll
        for (int it = 0; it < 16; ++it) {
            const int j = (it * 64 + lane) * 4;      // 0..4092
            const float4 v = *(const float4*)(fp + j);
            const float f4 = (j + 4 < S_LEN) ? fp[j + 4] : 0.f;
            frx[4094 - j] = f2bf(v.y) | (f2bf(v.x) << 16);
            frx[4093 - j] = f2bf(v.z) | (f2bf(v.y) << 16);
            frx[4092 - j] = f2bf(v.w) | (f2bf(v.z) << 16);
            if (j < 4092) frx[4091 - j] = f2bf(f4) | (f2bf(v.w) << 16);
        }
    }
    __syncthreads();

    const int m    = lane & 15;
    const int quad = lane >> 4;

    f32x4 acc[4][4];
#pragma unroll
    for (int mt = 0; mt < 4; ++mt)
#pragma unroll
        for (int pt = 0; pt < 4; ++pt)
#pragma unroll
            for (int e = 0; e < 4; ++e) acc[mt][pt][e] = 0.f;

    const int eA_base = 4095 - m + quad * 8;                 // - 64r - 16mt + 32kc
    const int oB_base = XS_PAD + 64 * m + quad * 8;          // + 1024pt - 64r + 32kc

    for (int r = 0; r < 64; ++r) {
        const int ea_r = eA_base - 64 * r;
        short8 afr[4][2];
#pragma unroll
        for (int mt = 0; mt < 4; ++mt)
#pragma unroll
            for (int kc = 0; kc < 2; ++kc) {
                const int e = ea_r - 16 * mt + 32 * kc;
                union { unsigned int u[4]; short8 s; } cvt;
                cvt.u[0] = frx[e];
                cvt.u[1] = frx[e + 2];
                cvt.u[2] = frx[e + 4];
                cvt.u[3] = frx[e + 6];
                afr[mt][kc] = cvt.s;
            }
        const int ptmin = r >> 4;
        const int ob_r = oB_base - 64 * r;
#pragma unroll
        for (int pt = 0; pt < 4; ++pt) {
            if (pt >= ptmin) {
                const int o0 = ob_r + 1024 * pt;
                const short8 bfr0 = *(const short8*)(xs + xsw(o0 >> 3) * 8);
                const short8 bfr1 = *(const short8*)(xs + xsw((o0 + 32) >> 3) * 8);
#pragma unroll
                for (int mt = 0; mt < 4; ++mt) {
                    acc[mt][pt] = __builtin_amdgcn_mfma_f32_16x16x32_bf16(afr[mt][0], bfr0, acc[mt][pt], 0, 0, 0);
                    acc[mt][pt] = __builtin_amdgcn_mfma_f32_16x16x32_bf16(afr[mt][1], bfr1, acc[mt][pt], 0, 0, 0);
                }
            }
        }
    }

    // ---- epilogue: out[s] = z[s] * acc * (1/8192) ----
    const float inv = 1.f / 8192.f;
#pragma unroll
    for (int mt = 0; mt < 4; ++mt)
#pragma unroll
        for (int pt = 0; pt < 4; ++pt) {
            const int p  = 16 * pt + m;
            const int s0 = 64 * p + 16 * mt + quad * 4;     // rows q = s0..s0+3
            const float4 z4 = *(const float4*)(zp + s0);
            float4 o4;
            o4.x = z4.x * acc[mt][pt][0] * inv;
            o4.y = z4.y * acc[mt][pt][1] * inv;
            o4.z = z4.z * acc[mt][pt][2] * inv;
            o4.w = z4.w * acc[mt][pt][3] * inv;
            *(float4*)(op + s0) = o4;
        }
}

// ---------------- out[b][s][e] = mask * (sum_d v[b][d][s] * W_out[d][e] + b_out[e]) ----------------
__global__ __launch_bounds__(256) void k_out(
    const float* __restrict__ v, const float* __restrict__ Wo,
    const float* __restrict__ bo, const int* __restrict__ pos,
    float* __restrict__ out)
{
    const int b   = blockIdx.y;
    const int s0  = blockIdx.x * 32;
    const int tid = threadIdx.x;
    __shared__ float vs[256 * 36];
    {
        const float4* src = (const float4*)(v + ((size_t)(b*256 + tid)) * S_LEN + s0);
#pragma unroll
        for (int q = 0; q < 8; ++q) {
            *(float4*)&vs[tid*36 + q*4] = src[q];
        }
    }
    __syncthreads();
    float acc[32];
#pragma unroll
    for (int r = 0; r < 32; ++r) acc[r] = 0.f;
    for (int dd = 0; dd < 256; ++dd) {
        const float w = Wo[(size_t)dd * 256 + tid];
        const float* vr = &vs[dd * 36];
#pragma unroll
        for (int q = 0; q < 8; ++q) {
            const float4 x4 = *(const float4*)&vr[q*4];
            acc[q*4+0] += x4.x * w;
            acc[q*4+1] += x4.y * w;
            acc[q*4+2] += x4.z * w;
            acc[q*4+3] += x4.w * w;
        }
    }
    const float bb = bo[tid];
#pragma unroll
    for (int r = 0; r < 32; ++r) {
        const int s = s0 + r;
        const float m = (pos[(size_t)b * S_LEN + s] != -1) ? 1.f : 0.f;
        out[((size_t)b * S_LEN + s) * 256 + tid] = (acc[r] + bb) * m;
    }
}

extern "C" void kernel_launch(void* const* d_in, const int* in_sizes, int n_in,
                              void* d_out, int out_size, void* d_ws, size_t ws_size,
                              hipStream_t stream) {
    const float* emb = (const float*)d_in[0];
    const int*   pos = (const int*)  d_in[1];
    const float* Wp  = (const float*)d_in[2];
    const float* cw  = (const float*)d_in[3];
    const float* cb  = (const float*)d_in[4];
    const float* W1  = (const float*)d_in[5];
    const float* b1  = (const float*)d_in[6];
    const float* lg  = (const float*)d_in[7];
    const float* lb  = (const float*)d_in[8];
    const float* W2  = (const float*)d_in[9];
    const float* b2  = (const float*)d_in[10];
    const float* ffs = (const float*)d_in[11];
    const float* Wo  = (const float*)d_in[12];
    const float* bo  = (const float*)d_in[13];

    float* ws   = (float*)d_ws;
    float* minp = ws + OFF_MINP;
    float* wpt  = ws + OFF_WPT;
    float* weff = ws + OFF_WEFF;
    float* c    = ws + OFF_C;
    float* hh   = ws + OFF_HH;
    float* vb   = ws + OFF_V;
    float* ub   = ws + OFF_U;

    k_minpos<<<dim3(8), dim3(256), 0, stream>>>(pos, minp);
    k_wpt<<<dim3(24, 8), dim3(256), 0, stream>>>(Wp, wpt);
    k_weff<<<dim3(768), dim3(256), 0, stream>>>(wpt, cw, weff);
    k_convgemm<<<dim3(32, 6, 8), dim3(256), 0, stream>>>(emb, pos, weff, cb, c);
    k_ff<<<dim3(256, 8), dim3(256), 0, stream>>>(emb, pos, minp, W1, b1, lg, lb, W2, b2, ffs, hh);
    // v = zs[2]; v = zs[0] * longconv(v, hh[:,0]); v = zs[1] * longconv(v, hh[:,1])
    k_conv_mfma<<<dim3(256, 8), dim3(64), 0, stream>>>(c, 768, 512, hh, 0, c, vb);
    k_conv_mfma<<<dim3(256, 8), dim3(64), 0, stream>>>(vb, 256, 0, hh, 1, c, ub);
    k_out<<<dim3(128, 8), dim3(256), 0, stream>>>(ub, Wo, bo, pos, (float*)d_out);
}

// Round 5
// 756.948 us; speedup vs baseline: 3.8359x; 1.4483x over previous
//
#include <hip/hip_runtime.h>
#include <cstdint>

#define S_LEN 4096
#define D_DIM 256

// workspace layout (float offsets)
#define OFF_MINP 0
#define OFF_WPT  16
#define OFF_WTH  (OFF_WPT + 768*256)     // WeffT hi, 768x768 ushort = 294912 floats
#define OFF_WTL  (OFF_WTH + 294912)      // WeffT lo
#define OFF_C    (OFF_WTL + 294912)      // == old OFF_C, downstream unchanged
#define OFF_HH   (OFF_C + 8*768*4096)
#define OFF_V    (OFF_HH + 8*2*256*4096)
#define OFF_U    (OFF_V + 8*256*4096)

typedef __attribute__((ext_vector_type(8))) short short8;
typedef __attribute__((ext_vector_type(4))) float f32x4;

__device__ __forceinline__ float wave_reduce_sum(float v) {
#pragma unroll
    for (int off = 32; off > 0; off >>= 1) v += __shfl_down(v, off, 64);
    return v;
}

__device__ __forceinline__ unsigned int f2bf(float x) {
    union { float f; unsigned int u; } v; v.f = x;
    unsigned int r = v.u + 0x7fffu + ((v.u >> 16) & 1u);   // RNE
    return r >> 16;
}
__device__ __forceinline__ float bf2f(unsigned int h) {
    union { unsigned int u; float f; } v; v.u = h << 16; return v.f;
}

// ---------------- min valid position per batch ----------------
__global__ __launch_bounds__(256) void k_minpos(const int* __restrict__ pos, float* __restrict__ minp)
{
    const int b = blockIdx.x;
    const int tid = threadIdx.x;
    int mn = 0x7fffffff;
    const int* p = pos + (size_t)b * S_LEN;
    for (int s = tid; s < S_LEN; s += 256) {
        const int v = p[s];
        if (v != -1) mn = min(mn, v);
    }
    __shared__ int red[256];
    red[tid] = mn;
    __syncthreads();
    for (int st = 128; st > 0; st >>= 1) {
        if (tid < st) red[tid] = min(red[tid], red[tid + st]);
        __syncthreads();
    }
    if (tid == 0) minp[b] = (float)red[0];
}

// ---------------- transpose W_proj (256x768) -> WpT (768x256) ----------------
__global__ __launch_bounds__(256) void k_wpt(const float* __restrict__ Wp, float* __restrict__ WpT)
{
    __shared__ float t[32][33];
    const int e0 = blockIdx.x * 32;   // 0..767
    const int d0 = blockIdx.y * 32;   // 0..255
    const int lx = threadIdx.x & 31, ly = threadIdx.x >> 5; // 32x8
#pragma unroll
    for (int q = 0; q < 4; ++q)
        t[ly + 8*q][lx] = Wp[(size_t)(d0 + ly + 8*q) * 768 + e0 + lx];
    __syncthreads();
#pragma unroll
    for (int q = 0; q < 4; ++q)
        WpT[(size_t)(e0 + ly + 8*q) * 256 + d0 + lx] = t[lx][ly + 8*q];
}

// ---------------- WeffT[o][t*256+d] = sum_i WpT[g*256+i][d] * conv_w[o][i][t], split hi/lo bf16 ----------------
__global__ __launch_bounds__(256) void k_weff(const float* __restrict__ WpT, const float* __restrict__ cw,
                                              unsigned short* __restrict__ wth, unsigned short* __restrict__ wtl)
{
    const int o = blockIdx.x;       // 768
    const int d = threadIdx.x;      // 256
    const int g = o >> 8;
    __shared__ float cwrow[768];
    for (int i = threadIdx.x; i < 768; i += 256) cwrow[i] = cw[(size_t)o * 768 + i];
    __syncthreads();
    float a0 = 0.f, a1 = 0.f, a2 = 0.f;
    const float* wb = WpT + (size_t)(g * 256) * 256 + d;
#pragma unroll 4
    for (int i = 0; i < 256; ++i) {
        const float wv = wb[(size_t)i * 256];
        a0 += wv * cwrow[i*3+0];
        a1 += wv * cwrow[i*3+1];
        a2 += wv * cwrow[i*3+2];
    }
    const float av[3] = {a0, a1, a2};
#pragma unroll
    for (int t = 0; t < 3; ++t) {
        const unsigned int hb = f2bf(av[t]);
        const unsigned int lb = f2bf(av[t] - bf2f(hb));
        wth[(size_t)o * 768 + t * 256 + d] = (unsigned short)hb;
        wtl[(size_t)o * 768 + t * 256 + d] = (unsigned short)lb;
    }
}

// ---------------- MFMA conv-GEMM: c[b][o][s] = mask*(conv_b[o] + sum_{t,d} emb[b][s+t-1][d]*Weff[t][d][o]) ----
// 128(s) x 128(o) block tile, 4 waves (each 32 s x 128 o), 3-pass bf16 split (AhBh+AhBl+AlBh ~ fp32).
// A-tile: 130 rows (s0-1 .. s0+128) x 32 d per chunk, shared across the 3 taps via +t row offset.
// Frag conventions identical to k_conv_mfma (verified R4): A[m=lane&15][k=quad*8+j] contiguous k,
// B[k=quad*8+j][n=lane&15] from [o][k] rows, C/D row = quad*4+reg (s), col = lane&15 (o).
#define CG_LDA 40   // 32 + 8 pad (keeps 16B frag alignment, spreads banks)
__global__ __launch_bounds__(256, 2) void k_convgemm(
    const float* __restrict__ emb, const int* __restrict__ pos,
    const unsigned short* __restrict__ wth, const unsigned short* __restrict__ wtl,
    const float* __restrict__ convb, float* __restrict__ c)
{
    const int b  = blockIdx.z;
    const int o0 = blockIdx.y * 128;
    const int s0 = blockIdx.x * 128;
    const int tid  = threadIdx.x;
    const int wave = tid >> 6, lane = tid & 63;
    const int m16  = lane & 15, quad = lane >> 4;

    __shared__ __align__(16) unsigned short Ah[130 * CG_LDA];
    __shared__ __align__(16) unsigned short Al[130 * CG_LDA];
    __shared__ __align__(16) unsigned short Bh[128 * CG_LDA];
    __shared__ __align__(16) unsigned short Bl[128 * CG_LDA];

    f32x4 acc[2][8];
#pragma unroll
    for (int mt = 0; mt < 2; ++mt)
#pragma unroll
        for (int nt = 0; nt < 8; ++nt)
#pragma unroll
            for (int e = 0; e < 4; ++e) acc[mt][nt][e] = 0.f;

    for (int c8 = 0; c8 < 8; ++c8) {
        for (int t = 0; t < 3; ++t) {
            if (t == 0) {
                // stage A chunk: rows 0..129 (emb rows s0-1..s0+128), 32 d
                for (int task = tid; task < 1040; task += 256) {
                    const int r = task >> 3;
                    const int g = task & 7;
                    const int srow = s0 + r - 1;
                    float4 v = make_float4(0.f, 0.f, 0.f, 0.f);
                    if (srow >= 0 && srow < S_LEN)
                        v = *(const float4*)(emb + ((size_t)b * S_LEN + srow) * D_DIM + c8 * 32 + g * 4);
                    const unsigned int hx = f2bf(v.x), hy = f2bf(v.y), hz = f2bf(v.z), hw = f2bf(v.w);
                    uint2 hp, lp;
                    hp.x = hx | (hy << 16);
                    hp.y = hz | (hw << 16);
                    lp.x = f2bf(v.x - bf2f(hx)) | (f2bf(v.y - bf2f(hy)) << 16);
                    lp.y = f2bf(v.z - bf2f(hz)) | (f2bf(v.w - bf2f(hw)) << 16);
                    *(uint2*)&Ah[r * CG_LDA + g * 4] = hp;
                    *(uint2*)&Al[r * CG_LDA + g * 4] = lp;
                }
            }
            // stage B chunk: 128 o-rows x 32 k (k = t*256 + c8*32 + ..)
            for (int task = tid; task < 512; task += 256) {
                const int r = task >> 2;
                const int g = task & 3;
                const size_t gi = (size_t)(o0 + r) * 768 + t * 256 + c8 * 32 + g * 8;
                *(uint4*)&Bh[r * CG_LDA + g * 8] = *(const uint4*)(wth + gi);
                *(uint4*)&Bl[r * CG_LDA + g * 8] = *(const uint4*)(wtl + gi);
            }
            __syncthreads();
            // MFMA segment
            short8 ah[2], al[2];
#pragma unroll
            for (int mt = 0; mt < 2; ++mt) {
                const int ar = (wave * 32 + mt * 16 + m16 + t) * CG_LDA + quad * 8;
                ah[mt] = *(const short8*)&Ah[ar];
                al[mt] = *(const short8*)&Al[ar];
            }
#pragma unroll
            for (int nt = 0; nt < 8; ++nt) {
                const int br = (nt * 16 + m16) * CG_LDA + quad * 8;
                const short8 bh = *(const short8*)&Bh[br];
                const short8 bl = *(const short8*)&Bl[br];
#pragma unroll
                for (int mt = 0; mt < 2; ++mt) {
                    acc[mt][nt] = __builtin_amdgcn_mfma_f32_16x16x32_bf16(ah[mt], bh, acc[mt][nt], 0, 0, 0);
                    acc[mt][nt] = __builtin_amdgcn_mfma_f32_16x16x32_bf16(ah[mt], bl, acc[mt][nt], 0, 0, 0);
                    acc[mt][nt] = __builtin_amdgcn_mfma_f32_16x16x32_bf16(al[mt], bh, acc[mt][nt], 0, 0, 0);
                }
            }
            __syncthreads();
        }
    }

    // epilogue: +bias, *mask, store c[b][o][s] (float4 over s)
    float msk[2][4];
#pragma unroll
    for (int mt = 0; mt < 2; ++mt) {
        const int s = s0 + wave * 32 + mt * 16 + quad * 4;
        const int4 p4 = *(const int4*)(pos + (size_t)b * S_LEN + s);
        msk[mt][0] = (p4.x != -1) ? 1.f : 0.f;
        msk[mt][1] = (p4.y != -1) ? 1.f : 0.f;
        msk[mt][2] = (p4.z != -1) ? 1.f : 0.f;
        msk[mt][3] = (p4.w != -1) ? 1.f : 0.f;
    }
#pragma unroll
    for (int nt = 0; nt < 8; ++nt) {
        const int o = o0 + nt * 16 + m16;
        const float cb = convb[o];
#pragma unroll
        for (int mt = 0; mt < 2; ++mt) {
            const int s = s0 + wave * 32 + mt * 16 + quad * 4;
            float4 r;
            r.x = (acc[mt][nt][0] + cb) * msk[mt][0];
            r.y = (acc[mt][nt][1] + cb) * msk[mt][1];
            r.z = (acc[mt][nt][2] + cb) * msk[mt][2];
            r.w = (acc[mt][nt][3] + cb) * msk[mt][3];
            *(float4*)(c + ((size_t)(b * 768 + o)) * S_LEN + s) = r;
        }
    }
}

// ---------------- RoPE + FF + L1-normalize -> hh[b][i][d][s] ----------------
__global__ __launch_bounds__(256) void k_ff(
    const float* __restrict__ emb, const int* __restrict__ pos, const float* __restrict__ minp,
    const float* __restrict__ W1, const float* __restrict__ b1,
    const float* __restrict__ lng, const float* __restrict__ lnb,
    const float* __restrict__ W2, const float* __restrict__ b2,
    const float* __restrict__ ffs, float* __restrict__ hh)
{
    const int b   = blockIdx.y;
    const int s0  = blockIdx.x * 16;
    const int tid = threadIdx.x;
    __shared__ float tls[16 * 256];
    __shared__ float hls[16 * 256];
    __shared__ float mu_s[16], rs_s[16], sm0[16], sm1[16];
    {
        const int r  = tid >> 4;
        const int j0 = (tid & 15) * 8;
        const int s  = s0 + r;
        const int p  = pos[(size_t)b * S_LEN + s];
        const float adj = (p == -1) ? -1.f : ((float)p - minp[b]);
        const float4* src = (const float4*)(emb + ((size_t)b * S_LEN + s) * D_DIM + j0 * 2);
        const float4 q0 = src[0], q1 = src[1], q2 = src[2], q3 = src[3];
        const float ev[16] = {q0.x,q0.y,q0.z,q0.w,q1.x,q1.y,q1.z,q1.w,
                              q2.x,q2.y,q2.z,q2.w,q3.x,q3.y,q3.z,q3.w};
        float* dst = &tls[r * 256 + j0 * 2];
#pragma unroll
        for (int jj = 0; jj < 8; ++jj) {
            const int j = j0 + jj;
            const float theta = expf(-(float)j * 0.07195578415606394f);
            float sn, cs;
            sincosf(adj * theta, &sn, &cs);
            const float x1 = ev[2*jj], x2 = ev[2*jj+1];
            dst[2*jj]   = x1 * cs - x2 * sn;
            dst[2*jj+1] = x1 * sn + x2 * cs;
        }
    }
    __syncthreads();
    float h1a[16];
#pragma unroll
    for (int r = 0; r < 16; ++r) h1a[r] = 0.f;
    for (int dd = 0; dd < 256; dd += 4) {
        const float w0 = W1[(size_t)(dd+0)*256 + tid];
        const float w1 = W1[(size_t)(dd+1)*256 + tid];
        const float w2 = W1[(size_t)(dd+2)*256 + tid];
        const float w3 = W1[(size_t)(dd+3)*256 + tid];
#pragma unroll
        for (int r = 0; r < 16; ++r) {
            const float4 t4 = *(const float4*)&tls[r*256 + dd];
            h1a[r] += t4.x*w0 + t4.y*w1 + t4.z*w2 + t4.w*w3;
        }
    }
    {
        const float bb = b1[tid];
#pragma unroll
        for (int r = 0; r < 16; ++r) hls[r*256 + tid] = h1a[r] + bb;
    }
    __syncthreads();
    {
        const int w = tid >> 6, lane = tid & 63;
#pragma unroll
        for (int rr = 0; rr < 4; ++rr) {
            const int r = w * 4 + rr;
            float s = 0.f, q = 0.f;
#pragma unroll
            for (int c4 = 0; c4 < 4; ++c4) {
                const float v = hls[r*256 + lane + c4*64];
                s += v; q += v*v;
            }
            s = wave_reduce_sum(s);
            q = wave_reduce_sum(q);
            if (lane == 0) {
                const float mu = s * (1.f/256.f);
                const float var = q * (1.f/256.f) - mu*mu;
                mu_s[r] = mu;
                rs_s[r] = rsqrtf(var + 1e-5f);
            }
        }
    }
    __syncthreads();
    {
        const float g = lng[tid], be = lnb[tid];
#pragma unroll
        for (int r = 0; r < 16; ++r) {
            const float h = (hls[r*256 + tid] - mu_s[r]) * rs_s[r] * g + be;
            tls[r*256 + tid] = 0.5f * h * (1.f + erff(h * 0.7071067811865475f));
        }
    }
    __syncthreads();
    float a0[16], a1[16];
#pragma unroll
    for (int r = 0; r < 16; ++r) { a0[r] = 0.f; a1[r] = 0.f; }
    for (int ee = 0; ee < 256; ee += 4) {
        float wA[4], wB[4];
#pragma unroll
        for (int q = 0; q < 4; ++q) {
            wA[q] = W2[(size_t)(ee+q)*512 + tid];
            wB[q] = W2[(size_t)(ee+q)*512 + tid + 256];
        }
#pragma unroll
        for (int r = 0; r < 16; ++r) {
            const float4 h4 = *(const float4*)&tls[r*256 + ee];
            a0[r] += h4.x*wA[0] + h4.y*wA[1] + h4.z*wA[2] + h4.w*wA[3];
            a1[r] += h4.x*wB[0] + h4.y*wB[1] + h4.z*wB[2] + h4.w*wB[3];
        }
    }
    {
        const float bA = b2[tid], bB = b2[tid+256];
        const float fA = ffs[tid], fB = ffs[tid+256];
#pragma unroll
        for (int r = 0; r < 16; ++r) {
            a0[r] = (a0[r] + bA) * fA;
            a1[r] = (a1[r] + bB) * fB;
        }
    }
#pragma unroll
    for (int r = 0; r < 16; ++r) hls[r*256 + tid] = fabsf(a0[r]);
    __syncthreads();
    {
        const int w = tid >> 6, lane = tid & 63;
#pragma unroll
        for (int rr = 0; rr < 4; ++rr) {
            const int r = w*4 + rr;
            float s = 0.f;
#pragma unroll
            for (int c4 = 0; c4 < 4; ++c4) s += hls[r*256 + lane + c4*64];
            s = wave_reduce_sum(s);
            if (lane == 0) sm0[r] = s;
        }
    }
    __syncthreads();
#pragma unroll
    for (int r = 0; r < 16; ++r) hls[r*256 + tid] = fabsf(a1[r]);
    __syncthreads();
    {
        const int w = tid >> 6, lane = tid & 63;
#pragma unroll
        for (int rr = 0; rr < 4; ++rr) {
            const int r = w*4 + rr;
            float s = 0.f;
#pragma unroll
            for (int c4 = 0; c4 < 4; ++c4) s += hls[r*256 + lane + c4*64];
            s = wave_reduce_sum(s);
            if (lane == 0) sm1[r] = s;
        }
    }
    __syncthreads();
    {
        float* p0 = hh + ((size_t)((b*2+0)*256 + tid)) * S_LEN + s0;
        float* p1 = hh + ((size_t)((b*2+1)*256 + tid)) * S_LEN + s0;
#pragma unroll
        for (int r = 0; r < 16; ++r) {
            p0[r] = a0[r] / (sm0[r] + 1e-8f);
            p1[r] = a1[r] / (sm1[r] + 1e-8f);
        }
    }
}

// ---------------- MFMA blocked-Toeplitz causal long conv (unchanged from R4) ----------------
#define XS_PAD   960
#define XS_ELEMS 5056
#define FRX_WORDS 4160
__device__ __forceinline__ int xsw(int blk) { return blk ^ ((blk >> 3) & 7); }

__global__ __launch_bounds__(64) void k_conv_mfma(
    const float* __restrict__ xbuf, const int xC, const int xoff,
    const float* __restrict__ hh, const int iord,
    const float* __restrict__ cbuf, float* __restrict__ outb)
{
    const int d = blockIdx.x;
    const int b = blockIdx.y;
    const int lane = threadIdx.x;
    const float* xp = xbuf + ((size_t)(b * xC + xoff + d)) * S_LEN;
    const float* fp = hh   + ((size_t)((b * 2 + iord) * 256 + d)) * S_LEN;
    const float* zp = cbuf + ((size_t)(b * 768 + iord * 256 + d)) * S_LEN;
    float* op = outb + ((size_t)(b * 256 + d)) * S_LEN;

    __shared__ unsigned short xs[XS_ELEMS];
    __shared__ unsigned int   frx[FRX_WORDS];

    {
        for (int blk = lane; blk < 120; blk += 64) {
            int4 z; z.x = 0; z.y = 0; z.z = 0; z.w = 0;
            *(int4*)(xs + xsw(blk) * 8) = z;
        }
#pragma unroll
        for (int it = 0; it < 8; ++it) {
            const int idx = it * 64 + lane;
            const int j = idx * 8;
            const float4 v0 = *(const float4*)(xp + j);
            const float4 v1 = *(const float4*)(xp + j + 4);
            int4 w;
            w.x = (int)(f2bf(v0.x) | (f2bf(v0.y) << 16));
            w.y = (int)(f2bf(v0.z) | (f2bf(v0.w) << 16));
            w.z = (int)(f2bf(v1.x) | (f2bf(v1.y) << 16));
            w.w = (int)(f2bf(v1.z) | (f2bf(v1.w) << 16));
            *(int4*)(xs + xsw(120 + idx) * 8) = w;
        }
    }
    {
        frx[4096 + lane] = 0u;
        if (lane == 0) frx[4095] = f2bf(fp[0]);
#pragma unroll
        for (int it = 0; it < 16; ++it) {
            const int j = (it * 64 + lane) * 4;
            const float4 v = *(const float4*)(fp + j);
            const float f4 = (j + 4 < S_LEN) ? fp[j + 4] : 0.f;
            frx[4094 - j] = f2bf(v.y) | (f2bf(v.x) << 16);
            frx[4093 - j] = f2bf(v.z) | (f2bf(v.y) << 16);
            frx[4092 - j] = f2bf(v.w) | (f2bf(v.z) << 16);
            if (j < 4092) frx[4091 - j] = f2bf(f4) | (f2bf(v.w) << 16);
        }
    }
    __syncthreads();

    const int m    = lane & 15;
    const int quad = lane >> 4;

    f32x4 acc[4][4];
#pragma unroll
    for (int mt = 0; mt < 4; ++mt)
#pragma unroll
        for (int pt = 0; pt < 4; ++pt)
#pragma unroll
            for (int e = 0; e < 4; ++e) acc[mt][pt][e] = 0.f;

    const int eA_base = 4095 - m + quad * 8;
    const int oB_base = XS_PAD + 64 * m + quad * 8;

    for (int r = 0; r < 64; ++r) {
        const int ea_r = eA_base - 64 * r;
        short8 afr[4][2];
#pragma unroll
        for (int mt = 0; mt < 4; ++mt)
#pragma unroll
            for (int kc = 0; kc < 2; ++kc) {
                const int e = ea_r - 16 * mt + 32 * kc;
                union { unsigned int u[4]; short8 s; } cvt;
                cvt.u[0] = frx[e];
                cvt.u[1] = frx[e + 2];
                cvt.u[2] = frx[e + 4];
                cvt.u[3] = frx[e + 6];
                afr[mt][kc] = cvt.s;
            }
        const int ptmin = r >> 4;
        const int ob_r = oB_base - 64 * r;
#pragma unroll
        for (int pt = 0; pt < 4; ++pt) {
            if (pt >= ptmin) {
                const int o0 = ob_r + 1024 * pt;
                const short8 bfr0 = *(const short8*)(xs + xsw(o0 >> 3) * 8);
                const short8 bfr1 = *(const short8*)(xs + xsw((o0 + 32) >> 3) * 8);
#pragma unroll
                for (int mt = 0; mt < 4; ++mt) {
                    acc[mt][pt] = __builtin_amdgcn_mfma_f32_16x16x32_bf16(afr[mt][0], bfr0, acc[mt][pt], 0, 0, 0);
                    acc[mt][pt] = __builtin_amdgcn_mfma_f32_16x16x32_bf16(afr[mt][1], bfr1, acc[mt][pt], 0, 0, 0);
                }
            }
        }
    }

    const float inv = 1.f / 8192.f;
#pragma unroll
    for (int mt = 0; mt < 4; ++mt)
#pragma unroll
        for (int pt = 0; pt < 4; ++pt) {
            const int p  = 16 * pt + m;
            const int s0 = 64 * p + 16 * mt + quad * 4;
            const float4 z4 = *(const float4*)(zp + s0);
            float4 o4;
            o4.x = z4.x * acc[mt][pt][0] * inv;
            o4.y = z4.y * acc[mt][pt][1] * inv;
            o4.z = z4.z * acc[mt][pt][2] * inv;
            o4.w = z4.w * acc[mt][pt][3] * inv;
            *(float4*)(op + s0) = o4;
        }
}

// ---------------- out[b][s][e] = mask * (sum_d v[b][d][s] * W_out[d][e] + b_out[e]) ----------------
__global__ __launch_bounds__(256) void k_out(
    const float* __restrict__ v, const float* __restrict__ Wo,
    const float* __restrict__ bo, const int* __restrict__ pos,
    float* __restrict__ out)
{
    const int b   = blockIdx.y;
    const int s0  = blockIdx.x * 32;
    const int tid = threadIdx.x;
    __shared__ float vs[256 * 36];
    {
        const float4* src = (const float4*)(v + ((size_t)(b*256 + tid)) * S_LEN + s0);
#pragma unroll
        for (int q = 0; q < 8; ++q) {
            *(float4*)&vs[tid*36 + q*4] = src[q];
        }
    }
    __syncthreads();
    float acc[32];
#pragma unroll
    for (int r = 0; r < 32; ++r) acc[r] = 0.f;
    for (int dd = 0; dd < 256; ++dd) {
        const float w = Wo[(size_t)dd * 256 + tid];
        const float* vr = &vs[dd * 36];
#pragma unroll
        for (int q = 0; q < 8; ++q) {
            const float4 x4 = *(const float4*)&vr[q*4];
            acc[q*4+0] += x4.x * w;
            acc[q*4+1] += x4.y * w;
            acc[q*4+2] += x4.z * w;
            acc[q*4+3] += x4.w * w;
        }
    }
    const float bb = bo[tid];
#pragma unroll
    for (int r = 0; r < 32; ++r) {
        const int s = s0 + r;
        const float m = (pos[(size_t)b * S_LEN + s] != -1) ? 1.f : 0.f;
        out[((size_t)b * S_LEN + s) * 256 + tid] = (acc[r] + bb) * m;
    }
}

extern "C" void kernel_launch(void* const* d_in, const int* in_sizes, int n_in,
                              void* d_out, int out_size, void* d_ws, size_t ws_size,
                              hipStream_t stream) {
    const float* emb = (const float*)d_in[0];
    const int*   pos = (const int*)  d_in[1];
    const float* Wp  = (const float*)d_in[2];
    const float* cw  = (const float*)d_in[3];
    const float* cb  = (const float*)d_in[4];
    const float* W1  = (const float*)d_in[5];
    const float* b1  = (const float*)d_in[6];
    const float* lg  = (const float*)d_in[7];
    const float* lb  = (const float*)d_in[8];
    const float* W2  = (const float*)d_in[9];
    const float* b2  = (const float*)d_in[10];
    const float* ffs = (const float*)d_in[11];
    const float* Wo  = (const float*)d_in[12];
    const float* bo  = (const float*)d_in[13];

    float* ws   = (float*)d_ws;
    float* minp = ws + OFF_MINP;
    float* wpt  = ws + OFF_WPT;
    unsigned short* wth = (unsigned short*)(ws + OFF_WTH);
    unsigned short* wtl = (unsigned short*)(ws + OFF_WTL);
    float* c    = ws + OFF_C;
    float* hh   = ws + OFF_HH;
    float* vb   = ws + OFF_V;
    float* ub   = ws + OFF_U;

    k_minpos<<<dim3(8), dim3(256), 0, stream>>>(pos, minp);
    k_wpt<<<dim3(24, 8), dim3(256), 0, stream>>>(Wp, wpt);
    k_weff<<<dim3(768), dim3(256), 0, stream>>>(wpt, cw, wth, wtl);
    k_convgemm<<<dim3(32, 6, 8), dim3(256), 0, stream>>>(emb, pos, wth, wtl, cb, c);
    k_ff<<<dim3(256, 8), dim3(256), 0, stream>>>(emb, pos, minp, W1, b1, lg, lb, W2, b2, ffs, hh);
    // v = zs[2]; v = zs[0] * longconv(v, hh[:,0]); v = zs[1] * longconv(v, hh[:,1])
    k_conv_mfma<<<dim3(256, 8), dim3(64), 0, stream>>>(c, 768, 512, hh, 0, c, vb);
    k_conv_mfma<<<dim3(256, 8), dim3(64), 0, stream>>>(vb, 256, 0, hh, 1, c, ub);
    k_out<<<dim3(128, 8), dim3(256), 0, stream>>>(ub, Wo, bo, pos, (float*)d_out);
}